// Round 1
// 940.312 us; speedup vs baseline: 2.7637x; 2.7637x over previous
//
#include <hip/hip_runtime.h>
#include <cstdint>
#include <cstddef>

// Shapes (fixed): B=64, N=4, P=128, d=h=256, totP=512, feat=131072
#define P_    128
#define H_    256
#define FEAT_ 131072

// ---------------------------------------------------------------------------
// xn: row-normalize x. One block per row (32768 rows), 64 threads, LDS tree.
// ---------------------------------------------------------------------------
__global__ __launch_bounds__(64) void k_xn(
    const float* __restrict__ x, float* __restrict__ xn) {
  __shared__ float red[64];
  const int row = blockIdx.x, t = threadIdx.x;
  const float* xr = x + (size_t)row * 256;
  float ss = 0.f;
  for (int d = t; d < 256; d += 64) { float v = xr[d]; ss += v * v; }
  red[t] = ss; __syncthreads();
  for (int s = 32; s; s >>= 1) { if (t < s) red[t] += red[t + s]; __syncthreads(); }
  const float inv = 1.0f / fmaxf(sqrtf(red[0]), 1e-12f);
  for (int d = t; d < 256; d += 64) xn[(size_t)row * 256 + d] = xr[d] * inv;
}

// ---------------------------------------------------------------------------
// Fused sim + deg + sym-normalize. One block per blk (256 blocks, 256 thr).
// Per thread: 8x8 register tile of the 128x128 sim matrix; K=256 staged in
// LDS transposed [k][row] so A/B fragments are ds_read_b128.
//   raw[p][q] = (p==q) ? 0 : ((xn_p.xn_q)+1)*0.5*mask[p][q]
//   deg[p]    = 1 + sum_q raw[p][q] ;  dinv = rsqrt(max(deg,eps))
//   An[p][q]  = (p==q) ? dp*dq : raw*dp*dq
// ---------------------------------------------------------------------------
__global__ __launch_bounds__(256) void k_simfused(
    const float* __restrict__ xn, const float* __restrict__ mask,
    float* __restrict__ An) {
  __shared__ float Xs[16][128];      // [k][row], chunk of K
  __shared__ float red[128][17];     // row partial sums (pad 17: no bank hit)
  __shared__ float dinv_s[128];
  const int blk = blockIdx.x;
  const int t = threadIdx.x;
  const int tp = t >> 4, tq = t & 15;   // rows tp*8..+7, cols tq*8..+7
  const float* Xb = xn + (size_t)blk * (128 * 256);

  float v[8][8];
  #pragma unroll
  for (int i = 0; i < 8; ++i)
    #pragma unroll
    for (int j = 0; j < 8; ++j) v[i][j] = 0.f;

  for (int kc = 0; kc < 16; ++kc) {     // K chunks of 16, ascending k order
    __syncthreads();
    #pragma unroll
    for (int l = 0; l < 2; ++l) {       // stage 128 rows x 16 k
      const int f = t + 256 * l;
      const int row = f >> 2, k4 = (f & 3) * 4;
      const float4 x4 = *(const float4*)(Xb + (size_t)row * 256 + kc * 16 + k4);
      Xs[k4 + 0][row] = x4.x;
      Xs[k4 + 1][row] = x4.y;
      Xs[k4 + 2][row] = x4.z;
      Xs[k4 + 3][row] = x4.w;
    }
    __syncthreads();
    #pragma unroll
    for (int k = 0; k < 16; ++k) {
      const float4 a0 = *(const float4*)&Xs[k][tp * 8];
      const float4 a1 = *(const float4*)&Xs[k][tp * 8 + 4];
      const float4 b0 = *(const float4*)&Xs[k][tq * 8];
      const float4 b1 = *(const float4*)&Xs[k][tq * 8 + 4];
      const float a[8] = {a0.x, a0.y, a0.z, a0.w, a1.x, a1.y, a1.z, a1.w};
      const float b[8] = {b0.x, b0.y, b0.z, b0.w, b1.x, b1.y, b1.z, b1.w};
      #pragma unroll
      for (int i = 0; i < 8; ++i)
        #pragma unroll
        for (int j = 0; j < 8; ++j) v[i][j] += a[i] * b[j];
    }
  }

  // mask + diag-zero, and per-row partial sums for deg
  #pragma unroll
  for (int i = 0; i < 8; ++i) {
    const int r = tp * 8 + i;
    const float4 m0 = *(const float4*)(mask + r * 128 + tq * 8);
    const float4 m1 = *(const float4*)(mask + r * 128 + tq * 8 + 4);
    const float mm[8] = {m0.x, m0.y, m0.z, m0.w, m1.x, m1.y, m1.z, m1.w};
    float s = 0.f;
    #pragma unroll
    for (int j = 0; j < 8; ++j) {
      const int c = tq * 8 + j;
      const float vv = (r == c) ? 0.0f : (v[i][j] + 1.0f) * 0.5f * mm[j];
      v[i][j] = vv;
      s += vv;
    }
    red[r][tq] = s;
  }
  __syncthreads();
  if (t < 128) {
    float sm = 0.f;
    #pragma unroll
    for (int u = 0; u < 16; ++u) sm += red[t][u];
    const float deg = 1.0f + sm;
    dinv_s[t] = (deg > 0.0f) ? rsqrtf(fmaxf(deg, 1e-12f)) : 0.0f;
  }
  __syncthreads();

  float dq[8];
  #pragma unroll
  for (int j = 0; j < 8; ++j) dq[j] = dinv_s[tq * 8 + j];
  float* Ab = An + (size_t)blk * 16384;
  #pragma unroll
  for (int i = 0; i < 8; ++i) {
    const int r = tp * 8 + i;
    const float dp = dinv_s[r];
    float o[8];
    #pragma unroll
    for (int j = 0; j < 8; ++j) {
      const int c = tq * 8 + j;
      o[j] = (r == c) ? dp * dq[j] : v[i][j] * dp * dq[j];
    }
    *(float4*)(Ab + (size_t)r * 128 + tq * 8)     = make_float4(o[0], o[1], o[2], o[3]);
    *(float4*)(Ab + (size_t)r * 128 + tq * 8 + 4) = make_float4(o[4], o[5], o[6], o[7]);
  }
}

// ---------------------------------------------------------------------------
// Tiled GEMM: out[32768][256] = A[32768][256] @ W[256][256] + bias.
// Grid (256 rowblocks x 2 colblocks), 256 threads, 8x8 regs/thread,
// 128x128 tile, K staged in LDS transposed [k][row]/[k][col].
// ---------------------------------------------------------------------------
__global__ __launch_bounds__(256) void k_gemm_t(
    const float* __restrict__ A, const float* __restrict__ W,
    const float* __restrict__ bias, float* __restrict__ out) {
  __shared__ float As[16][128];   // [k][row]
  __shared__ float Ws[16][128];   // [k][col]
  const int rb = blockIdx.x, cb = blockIdx.y;
  const int t = threadIdx.x, tp = t >> 4, tq = t & 15;
  const int m0 = rb * 128, c0 = cb * 128;

  float acc[8][8];
  #pragma unroll
  for (int j = 0; j < 8; ++j) {
    const float bj = bias[c0 + tq * 8 + j];
    #pragma unroll
    for (int i = 0; i < 8; ++i) acc[i][j] = bj;
  }

  for (int kc = 0; kc < 16; ++kc) {   // K=256, chunks of 16, ascending
    __syncthreads();
    #pragma unroll
    for (int l = 0; l < 2; ++l) {     // stage A tile: 128 rows x 16 k
      const int f = t + 256 * l;
      const int row = f >> 2, k4 = (f & 3) * 4;
      const float4 a4 = *(const float4*)(A + (size_t)(m0 + row) * 256 + kc * 16 + k4);
      As[k4 + 0][row] = a4.x;
      As[k4 + 1][row] = a4.y;
      As[k4 + 2][row] = a4.z;
      As[k4 + 3][row] = a4.w;
    }
    #pragma unroll
    for (int l = 0; l < 2; ++l) {     // stage W tile: 16 k x 128 cols
      const int f = t + 256 * l;
      const int k = f >> 5, c4 = (f & 31) * 4;
      const float4 w4 = *(const float4*)(W + (size_t)(kc * 16 + k) * 256 + c0 + c4);
      *(float4*)&Ws[k][c4] = w4;
    }
    __syncthreads();
    #pragma unroll
    for (int k = 0; k < 16; ++k) {
      const float4 a0 = *(const float4*)&As[k][tp * 8];
      const float4 a1 = *(const float4*)&As[k][tp * 8 + 4];
      const float4 w0 = *(const float4*)&Ws[k][tq * 8];
      const float4 w1 = *(const float4*)&Ws[k][tq * 8 + 4];
      const float a[8] = {a0.x, a0.y, a0.z, a0.w, a1.x, a1.y, a1.z, a1.w};
      const float w[8] = {w0.x, w0.y, w0.z, w0.w, w1.x, w1.y, w1.z, w1.w};
      #pragma unroll
      for (int i = 0; i < 8; ++i)
        #pragma unroll
        for (int j = 0; j < 8; ++j) acc[i][j] += a[i] * w[j];
    }
  }

  #pragma unroll
  for (int i = 0; i < 8; ++i) {
    float* orow = out + (size_t)(m0 + tp * 8 + i) * 256 + c0 + tq * 8;
    *(float4*)(orow)     = make_float4(acc[i][0], acc[i][1], acc[i][2], acc[i][3]);
    *(float4*)(orow + 4) = make_float4(acc[i][4], acc[i][5], acc[i][6], acc[i][7]);
  }
}

// ---------------------------------------------------------------------------
// Tiled bmm: out[blk*128+p][c] = sum_q An[blk][p][q] * XW[blk*128+q][c]
// Grid (256 blks x 2 colblocks), same tile structure, K=128.
// ---------------------------------------------------------------------------
__global__ __launch_bounds__(256) void k_bmm_t(
    const float* __restrict__ An, const float* __restrict__ XW,
    float* __restrict__ out) {
  __shared__ float As[16][128];   // [q][p]
  __shared__ float Ws[16][128];   // [q][c]
  const int blk = blockIdx.x, cb = blockIdx.y;
  const int t = threadIdx.x, tp = t >> 4, tq = t & 15;
  const float* Ab = An + (size_t)blk * 16384;        // [128][128]
  const float* Xb = XW + (size_t)blk * (128 * 256);  // [128][256]

  float acc[8][8];
  #pragma unroll
  for (int i = 0; i < 8; ++i)
    #pragma unroll
    for (int j = 0; j < 8; ++j) acc[i][j] = 0.f;

  for (int kc = 0; kc < 8; ++kc) {    // K=128, chunks of 16, ascending q
    __syncthreads();
    #pragma unroll
    for (int l = 0; l < 2; ++l) {     // stage An tile: 128 p x 16 q
      const int f = t + 256 * l;
      const int row = f >> 2, k4 = (f & 3) * 4;
      const float4 a4 = *(const float4*)(Ab + (size_t)row * 128 + kc * 16 + k4);
      As[k4 + 0][row] = a4.x;
      As[k4 + 1][row] = a4.y;
      As[k4 + 2][row] = a4.z;
      As[k4 + 3][row] = a4.w;
    }
    #pragma unroll
    for (int l = 0; l < 2; ++l) {     // stage XW tile: 16 q x 128 c
      const int f = t + 256 * l;
      const int k = f >> 5, c4 = (f & 31) * 4;
      const float4 w4 = *(const float4*)(Xb + (size_t)(kc * 16 + k) * 256 + cb * 128 + c4);
      *(float4*)&Ws[k][c4] = w4;
    }
    __syncthreads();
    #pragma unroll
    for (int k = 0; k < 16; ++k) {
      const float4 a0 = *(const float4*)&As[k][tp * 8];
      const float4 a1 = *(const float4*)&As[k][tp * 8 + 4];
      const float4 w0 = *(const float4*)&Ws[k][tq * 8];
      const float4 w1 = *(const float4*)&Ws[k][tq * 8 + 4];
      const float a[8] = {a0.x, a0.y, a0.z, a0.w, a1.x, a1.y, a1.z, a1.w};
      const float w[8] = {w0.x, w0.y, w0.z, w0.w, w1.x, w1.y, w1.z, w1.w};
      #pragma unroll
      for (int i = 0; i < 8; ++i)
        #pragma unroll
        for (int j = 0; j < 8; ++j) acc[i][j] += a[i] * w[j];
    }
  }

  #pragma unroll
  for (int i = 0; i < 8; ++i) {
    float* orow = out + (size_t)(blk * 128 + tp * 8 + i) * 256 + cb * 128 + tq * 8;
    *(float4*)(orow)     = make_float4(acc[i][0], acc[i][1], acc[i][2], acc[i][3]);
    *(float4*)(orow + 4) = make_float4(acc[i][4], acc[i][5], acc[i][6], acc[i][7]);
  }
}

// ---------------------------------------------------------------------------
// bn stats, coalesced two-pass: 256 blocks each reduce a 128-row stripe
// (lane = channel), partials to scratch; tiny final reduce. Deterministic.
// ---------------------------------------------------------------------------
__global__ __launch_bounds__(256) void k_bnpart(
    const float* __restrict__ pre, float* __restrict__ part) {
  const int b = blockIdx.x, c = threadIdx.x;
  const float* p0 = pre + (size_t)b * 128 * 256;
  float s = 0.f, s2 = 0.f;
  for (int r = 0; r < 128; ++r) {
    const float v = p0[(size_t)r * 256 + c];
    s += v; s2 += v * v;
  }
  part[b * 512 + c]       = s;
  part[b * 512 + 256 + c] = s2;
}

__global__ __launch_bounds__(256) void k_bnfinal(
    const float* __restrict__ part, float* __restrict__ st) {
  const int c = threadIdx.x;
  float s = 0.f, s2 = 0.f;
  for (int b = 0; b < 256; ++b) {
    s  += part[b * 512 + c];
    s2 += part[b * 512 + 256 + c];
  }
  st[c] = s; st[256 + c] = s2;
}

// ---------------------------------------------------------------------------
// bn_apply: out = relu(g*(pre-m)/sqrt(v+eps)+be), out-of-place.
// ---------------------------------------------------------------------------
__global__ __launch_bounds__(256) void k_bnapply(
    const float* __restrict__ pre, const float* __restrict__ st,
    const float* __restrict__ g, const float* __restrict__ be,
    float* __restrict__ out) {
  const int r = blockIdx.x, c = threadIdx.x;
  const float m = st[c] * (1.0f / 32768.0f);
  const float var = st[256 + c] * (1.0f / 32768.0f) - m * m;
  const float sc = g[c] * rsqrtf(var + 1e-5f);
  const float sh = be[c] - m * sc;
  const size_t i = (size_t)r * 256 + c;
  out[i] = fmaxf(pre[i] * sc + sh, 0.0f);
}

__global__ __launch_bounds__(256) void k_zero(float* __restrict__ z1) {
  z1[blockIdx.x * 256 + threadIdx.x] = 0.0f;
}

// ---------------------------------------------------------------------------
// head split-K GEMM: z1[64][128] += graph[64][131072] @ Wm1[131072][128]
// ---------------------------------------------------------------------------
__global__ __launch_bounds__(256) void k_headgemm(
    const float* __restrict__ graph, const float* __restrict__ Wm1,
    float* __restrict__ z1) {
  const int t = threadIdx.x;
  const int hg = t & 31;   // cols hg*4..+3
  const int bg = t >> 5;   // rows bg*8..+7
  float acc[8][4];
  #pragma unroll
  for (int i = 0; i < 8; ++i)
    #pragma unroll
    for (int j = 0; j < 4; ++j) acc[i][j] = 0.f;
  const int k0 = blockIdx.x * 1024;
  for (int kk = 0; kk < 1024; ++kk) {
    const int k = k0 + kk;
    float4 wv = *(const float4*)(Wm1 + (size_t)k * 128 + hg * 4);
    #pragma unroll
    for (int i = 0; i < 8; ++i) {
      float a = graph[(size_t)(bg * 8 + i) * FEAT_ + k];
      acc[i][0] += a * wv.x; acc[i][1] += a * wv.y;
      acc[i][2] += a * wv.z; acc[i][3] += a * wv.w;
    }
  }
  #pragma unroll
  for (int i = 0; i < 8; ++i)
    #pragma unroll
    for (int j = 0; j < 4; ++j)
      atomicAdd(&z1[(bg * 8 + i) * 128 + hg * 4 + j], acc[i][j]);
}

// ---------------------------------------------------------------------------
// head BN over batch (J features) + ReLU
// ---------------------------------------------------------------------------
template <int J>
__global__ __launch_bounds__(64) void k_headbn(
    const float* __restrict__ z, const float* __restrict__ g,
    const float* __restrict__ be, float* __restrict__ zr) {
  __shared__ float rs[64], rs2[64];
  const int j = blockIdx.x, b = threadIdx.x;
  const float v = z[b * J + j];
  rs[b] = v; rs2[b] = v * v; __syncthreads();
  for (int s = 32; s; s >>= 1) {
    if (b < s) { rs[b] += rs[b + s]; rs2[b] += rs2[b + s]; }
    __syncthreads();
  }
  const float m = rs[0] * (1.0f / 64.0f);
  const float var = rs2[0] * (1.0f / 64.0f) - m * m;
  const float sc = g[j] * rsqrtf(var + 1e-5f);
  const float sh = be[j] - m * sc;
  zr[b * J + j] = fmaxf(v * sc + sh, 0.0f);
}

__global__ __launch_bounds__(64) void k_headmm2(
    const float* __restrict__ zr1, const float* __restrict__ Wm2,
    float* __restrict__ z2) {
  const int b = blockIdx.x, j = threadIdx.x;
  float acc = 0.f;
  for (int k = 0; k < 128; ++k) acc += zr1[b * 128 + k] * Wm2[k * 64 + j];
  z2[b * 64 + j] = acc;
}

__global__ __launch_bounds__(128) void k_headout(
    const float* __restrict__ zr2, const float* __restrict__ Wm3,
    const float* __restrict__ bm3, float* __restrict__ out) {
  const int t = threadIdx.x;
  const int b = t >> 1, c = t & 1;
  float s = bm3[c];
  for (int k = 0; k < 64; ++k) s += zr2[b * 64 + k] * Wm3[k * 2 + c];
  out[t] = s;
}

// ---------------------------------------------------------------------------
extern "C" void kernel_launch(void* const* d_in, const int* in_sizes, int n_in,
                              void* d_out, int out_size, void* d_ws, size_t ws_size,
                              hipStream_t stream) {
  (void)in_sizes; (void)n_in; (void)out_size; (void)ws_size;
  const float* x    = (const float*)d_in[0];
  const float* mask = (const float*)d_in[1];
  const float* W1   = (const float*)d_in[2];
  const float* b1   = (const float*)d_in[3];
  const float* g1   = (const float*)d_in[4];
  const float* be1  = (const float*)d_in[5];
  const float* W2   = (const float*)d_in[6];
  const float* b2   = (const float*)d_in[7];
  const float* g2   = (const float*)d_in[8];
  const float* be2  = (const float*)d_in[9];
  const float* Wm1  = (const float*)d_in[10];
  // d_in[11] = bm1 (zeros; cancels under BN)
  const float* gm1  = (const float*)d_in[12];
  const float* bem1 = (const float*)d_in[13];
  const float* Wm2  = (const float*)d_in[14];
  // d_in[15] = bm2 (zeros; cancels under BN)
  const float* gm2  = (const float*)d_in[16];
  const float* bem2 = (const float*)d_in[17];
  const float* Wm3  = (const float*)d_in[18];
  const float* bm3  = (const float*)d_in[19];

  // workspace (floats), same layout as verified previously (117.67 MB)
  float* ws   = (float*)d_ws;
  float* T1   = ws;                 // 8,388,608 : xn -> h1 -> h2
  float* An   = T1 + 8388608;       // 4,194,304
  float* T2   = An + 4194304;       // 8,388,608 : XW1 -> XW2 (reused as bn partials)
  float* T3   = T2 + 8388608;       // 8,388,608 : pre1 -> pre2
  float* z1   = T3 + 8388608;       // 8,192
  float* dinv = z1 + 8192;          // 32,768 (unused now, kept for layout)
  float* st1  = dinv + 32768;       // 512
  float* st2  = st1 + 512;          // 512
  float* zr1  = st2 + 512;          // 8,192
  float* z2   = zr1 + 8192;         // 4,096
  float* zr2  = z2 + 4096;          // 4,096

  // edges / An (fused: sim + deg + normalize)
  k_xn<<<32768, 64, 0, stream>>>(x, T1);
  k_simfused<<<256, 256, 0, stream>>>(T1, mask, An);

  // layer 1
  k_gemm_t<<<dim3(256, 2), 256, 0, stream>>>(x, W1, b1, T2);
  k_bmm_t<<<dim3(256, 2), 256, 0, stream>>>(An, T2, T3);
  k_bnpart<<<256, 256, 0, stream>>>(T3, T2);     // T2 free after bmm
  k_bnfinal<<<1, 256, 0, stream>>>(T2, st1);
  k_bnapply<<<32768, 256, 0, stream>>>(T3, st1, g1, be1, T1);   // h1

  // layer 2
  k_gemm_t<<<dim3(256, 2), 256, 0, stream>>>(T1, W2, b2, T2);
  k_bmm_t<<<dim3(256, 2), 256, 0, stream>>>(An, T2, T3);
  k_bnpart<<<256, 256, 0, stream>>>(T3, T2);
  k_bnfinal<<<1, 256, 0, stream>>>(T2, st2);
  k_bnapply<<<32768, 256, 0, stream>>>(T3, st2, g2, be2, T1);   // h2

  // head
  k_zero<<<32, 256, 0, stream>>>(z1);
  k_headgemm<<<128, 256, 0, stream>>>(T1, Wm1, z1);
  k_headbn<128><<<128, 64, 0, stream>>>(z1, gm1, bem1, zr1);
  k_headmm2<<<64, 64, 0, stream>>>(zr1, Wm2, z2);
  k_headbn<64><<<64, 64, 0, stream>>>(z2, gm2, bem2, zr2);
  k_headout<<<1, 128, 0, stream>>>(zr2, Wm3, bm3, (float*)d_out);
}

// Round 2
// 555.947 us; speedup vs baseline: 4.6745x; 1.6914x over previous
//
#include <hip/hip_runtime.h>
#include <cstdint>
#include <cstddef>

// Shapes (fixed): B=64, N=4, P=128, d=h=256, totP=512, feat=131072
#define P_    128
#define H_    256
#define FEAT_ 131072

// ---------------------------------------------------------------------------
// xn: row-normalize x. 8192 blocks x 256 thr; one wave per row, float4 loads,
// wave-shuffle reduce (no LDS, no __syncthreads).
// ---------------------------------------------------------------------------
__global__ __launch_bounds__(256) void k_xn(
    const float* __restrict__ x, float* __restrict__ xn) {
  const int t = threadIdx.x;
  const int lane = t & 63;
  const int row = blockIdx.x * 4 + (t >> 6);
  const float* xr = x + (size_t)row * 256;
  const float4 v = *(const float4*)(xr + lane * 4);
  float ss = v.x * v.x + v.y * v.y + v.z * v.z + v.w * v.w;
  #pragma unroll
  for (int s = 32; s; s >>= 1) ss += __shfl_xor(ss, s, 64);
  const float inv = 1.0f / fmaxf(sqrtf(ss), 1e-12f);
  *(float4*)(xn + (size_t)row * 256 + lane * 4) =
      make_float4(v.x * inv, v.y * inv, v.z * inv, v.w * inv);
}

// ---------------------------------------------------------------------------
// Fused sim + deg + sym-normalize. One block per blk (256 blocks, 256 thr).
// Per thread: 8x8 register tile of the 128x128 sim matrix; K=256 staged in
// LDS transposed [k][row] so A/B fragments are ds_read_b128.
//   raw[p][q] = (p==q) ? 0 : ((xn_p.xn_q)+1)*0.5*mask[p][q]
//   deg[p]    = 1 + sum_q raw[p][q] ;  dinv = rsqrt(max(deg,eps))
//   An[p][q]  = (p==q) ? dp*dq : raw*dp*dq
// ---------------------------------------------------------------------------
__global__ __launch_bounds__(256) void k_simfused(
    const float* __restrict__ xn, const float* __restrict__ mask,
    float* __restrict__ An) {
  __shared__ float Xs[16][128];      // [k][row], chunk of K
  __shared__ float red[128][17];     // row partial sums (pad 17: no bank hit)
  __shared__ float dinv_s[128];
  const int blk = blockIdx.x;
  const int t = threadIdx.x;
  const int tp = t >> 4, tq = t & 15;   // rows tp*8..+7, cols tq*8..+7
  const float* Xb = xn + (size_t)blk * (128 * 256);

  float v[8][8];
  #pragma unroll
  for (int i = 0; i < 8; ++i)
    #pragma unroll
    for (int j = 0; j < 8; ++j) v[i][j] = 0.f;

  for (int kc = 0; kc < 16; ++kc) {     // K chunks of 16, ascending k order
    __syncthreads();
    #pragma unroll
    for (int l = 0; l < 2; ++l) {       // stage 128 rows x 16 k
      const int f = t + 256 * l;
      const int row = f >> 2, k4 = (f & 3) * 4;
      const float4 x4 = *(const float4*)(Xb + (size_t)row * 256 + kc * 16 + k4);
      Xs[k4 + 0][row] = x4.x;
      Xs[k4 + 1][row] = x4.y;
      Xs[k4 + 2][row] = x4.z;
      Xs[k4 + 3][row] = x4.w;
    }
    __syncthreads();
    #pragma unroll
    for (int k = 0; k < 16; ++k) {
      const float4 a0 = *(const float4*)&Xs[k][tp * 8];
      const float4 a1 = *(const float4*)&Xs[k][tp * 8 + 4];
      const float4 b0 = *(const float4*)&Xs[k][tq * 8];
      const float4 b1 = *(const float4*)&Xs[k][tq * 8 + 4];
      const float a[8] = {a0.x, a0.y, a0.z, a0.w, a1.x, a1.y, a1.z, a1.w};
      const float b[8] = {b0.x, b0.y, b0.z, b0.w, b1.x, b1.y, b1.z, b1.w};
      #pragma unroll
      for (int i = 0; i < 8; ++i)
        #pragma unroll
        for (int j = 0; j < 8; ++j) v[i][j] += a[i] * b[j];
    }
  }

  // mask + diag-zero, and per-row partial sums for deg
  #pragma unroll
  for (int i = 0; i < 8; ++i) {
    const int r = tp * 8 + i;
    const float4 m0 = *(const float4*)(mask + r * 128 + tq * 8);
    const float4 m1 = *(const float4*)(mask + r * 128 + tq * 8 + 4);
    const float mm[8] = {m0.x, m0.y, m0.z, m0.w, m1.x, m1.y, m1.z, m1.w};
    float s = 0.f;
    #pragma unroll
    for (int j = 0; j < 8; ++j) {
      const int c = tq * 8 + j;
      const float vv = (r == c) ? 0.0f : (v[i][j] + 1.0f) * 0.5f * mm[j];
      v[i][j] = vv;
      s += vv;
    }
    red[r][tq] = s;
  }
  __syncthreads();
  if (t < 128) {
    float sm = 0.f;
    #pragma unroll
    for (int u = 0; u < 16; ++u) sm += red[t][u];
    const float deg = 1.0f + sm;
    dinv_s[t] = (deg > 0.0f) ? rsqrtf(fmaxf(deg, 1e-12f)) : 0.0f;
  }
  __syncthreads();

  float dq[8];
  #pragma unroll
  for (int j = 0; j < 8; ++j) dq[j] = dinv_s[tq * 8 + j];
  float* Ab = An + (size_t)blk * 16384;
  #pragma unroll
  for (int i = 0; i < 8; ++i) {
    const int r = tp * 8 + i;
    const float dp = dinv_s[r];
    float o[8];
    #pragma unroll
    for (int j = 0; j < 8; ++j) {
      const int c = tq * 8 + j;
      o[j] = (r == c) ? dp * dq[j] : v[i][j] * dp * dq[j];
    }
    *(float4*)(Ab + (size_t)r * 128 + tq * 8)     = make_float4(o[0], o[1], o[2], o[3]);
    *(float4*)(Ab + (size_t)r * 128 + tq * 8 + 4) = make_float4(o[4], o[5], o[6], o[7]);
  }
}

// ---------------------------------------------------------------------------
// Tiled GEMM: out[32768][256] = A[32768][256] @ W[256][256] + bias.
// Grid (256 rowblocks x 2 colblocks), 256 threads, 8x8 regs/thread,
// 128x128 tile, K staged in LDS transposed [k][row]/[k][col].
// ---------------------------------------------------------------------------
__global__ __launch_bounds__(256) void k_gemm_t(
    const float* __restrict__ A, const float* __restrict__ W,
    const float* __restrict__ bias, float* __restrict__ out) {
  __shared__ float As[16][128];   // [k][row]
  __shared__ float Ws[16][128];   // [k][col]
  const int rb = blockIdx.x, cb = blockIdx.y;
  const int t = threadIdx.x, tp = t >> 4, tq = t & 15;
  const int m0 = rb * 128, c0 = cb * 128;

  float acc[8][8];
  #pragma unroll
  for (int j = 0; j < 8; ++j) {
    const float bj = bias[c0 + tq * 8 + j];
    #pragma unroll
    for (int i = 0; i < 8; ++i) acc[i][j] = bj;
  }

  for (int kc = 0; kc < 16; ++kc) {   // K=256, chunks of 16, ascending
    __syncthreads();
    #pragma unroll
    for (int l = 0; l < 2; ++l) {     // stage A tile: 128 rows x 16 k
      const int f = t + 256 * l;
      const int row = f >> 2, k4 = (f & 3) * 4;
      const float4 a4 = *(const float4*)(A + (size_t)(m0 + row) * 256 + kc * 16 + k4);
      As[k4 + 0][row] = a4.x;
      As[k4 + 1][row] = a4.y;
      As[k4 + 2][row] = a4.z;
      As[k4 + 3][row] = a4.w;
    }
    #pragma unroll
    for (int l = 0; l < 2; ++l) {     // stage W tile: 16 k x 128 cols
      const int f = t + 256 * l;
      const int k = f >> 5, c4 = (f & 31) * 4;
      const float4 w4 = *(const float4*)(W + (size_t)(kc * 16 + k) * 256 + c0 + c4);
      *(float4*)&Ws[k][c4] = w4;
    }
    __syncthreads();
    #pragma unroll
    for (int k = 0; k < 16; ++k) {
      const float4 a0 = *(const float4*)&As[k][tp * 8];
      const float4 a1 = *(const float4*)&As[k][tp * 8 + 4];
      const float4 w0 = *(const float4*)&Ws[k][tq * 8];
      const float4 w1 = *(const float4*)&Ws[k][tq * 8 + 4];
      const float a[8] = {a0.x, a0.y, a0.z, a0.w, a1.x, a1.y, a1.z, a1.w};
      const float w[8] = {w0.x, w0.y, w0.z, w0.w, w1.x, w1.y, w1.z, w1.w};
      #pragma unroll
      for (int i = 0; i < 8; ++i)
        #pragma unroll
        for (int j = 0; j < 8; ++j) acc[i][j] += a[i] * w[j];
    }
  }

  #pragma unroll
  for (int i = 0; i < 8; ++i) {
    float* orow = out + (size_t)(m0 + tp * 8 + i) * 256 + c0 + tq * 8;
    *(float4*)(orow)     = make_float4(acc[i][0], acc[i][1], acc[i][2], acc[i][3]);
    *(float4*)(orow + 4) = make_float4(acc[i][4], acc[i][5], acc[i][6], acc[i][7]);
  }
}

// ---------------------------------------------------------------------------
// Tiled bmm: out[blk*128+p][c] = sum_q An[blk][p][q] * XW[blk*128+q][c]
// Grid (256 blks x 2 colblocks), same tile structure, K=128.
// ---------------------------------------------------------------------------
__global__ __launch_bounds__(256) void k_bmm_t(
    const float* __restrict__ An, const float* __restrict__ XW,
    float* __restrict__ out) {
  __shared__ float As[16][128];   // [q][p]
  __shared__ float Ws[16][128];   // [q][c]
  const int blk = blockIdx.x, cb = blockIdx.y;
  const int t = threadIdx.x, tp = t >> 4, tq = t & 15;
  const float* Ab = An + (size_t)blk * 16384;        // [128][128]
  const float* Xb = XW + (size_t)blk * (128 * 256);  // [128][256]

  float acc[8][8];
  #pragma unroll
  for (int i = 0; i < 8; ++i)
    #pragma unroll
    for (int j = 0; j < 8; ++j) acc[i][j] = 0.f;

  for (int kc = 0; kc < 8; ++kc) {    // K=128, chunks of 16, ascending q
    __syncthreads();
    #pragma unroll
    for (int l = 0; l < 2; ++l) {     // stage An tile: 128 p x 16 q
      const int f = t + 256 * l;
      const int row = f >> 2, k4 = (f & 3) * 4;
      const float4 a4 = *(const float4*)(Ab + (size_t)row * 128 + kc * 16 + k4);
      As[k4 + 0][row] = a4.x;
      As[k4 + 1][row] = a4.y;
      As[k4 + 2][row] = a4.z;
      As[k4 + 3][row] = a4.w;
    }
    #pragma unroll
    for (int l = 0; l < 2; ++l) {     // stage XW tile: 16 q x 128 c
      const int f = t + 256 * l;
      const int k = f >> 5, c4 = (f & 31) * 4;
      const float4 w4 = *(const float4*)(Xb + (size_t)(kc * 16 + k) * 256 + cb * 128 + c4);
      *(float4*)&Ws[k][c4] = w4;
    }
    __syncthreads();
    #pragma unroll
    for (int k = 0; k < 16; ++k) {
      const float4 a0 = *(const float4*)&As[k][tp * 8];
      const float4 a1 = *(const float4*)&As[k][tp * 8 + 4];
      const float4 w0 = *(const float4*)&Ws[k][tq * 8];
      const float4 w1 = *(const float4*)&Ws[k][tq * 8 + 4];
      const float a[8] = {a0.x, a0.y, a0.z, a0.w, a1.x, a1.y, a1.z, a1.w};
      const float w[8] = {w0.x, w0.y, w0.z, w0.w, w1.x, w1.y, w1.z, w1.w};
      #pragma unroll
      for (int i = 0; i < 8; ++i)
        #pragma unroll
        for (int j = 0; j < 8; ++j) acc[i][j] += a[i] * w[j];
    }
  }

  #pragma unroll
  for (int i = 0; i < 8; ++i) {
    float* orow = out + (size_t)(blk * 128 + tp * 8 + i) * 256 + cb * 128 + tq * 8;
    *(float4*)(orow)     = make_float4(acc[i][0], acc[i][1], acc[i][2], acc[i][3]);
    *(float4*)(orow + 4) = make_float4(acc[i][4], acc[i][5], acc[i][6], acc[i][7]);
  }
}

// ---------------------------------------------------------------------------
// bn stats, coalesced two-pass: 256 blocks each reduce a 128-row stripe
// (lane = channel), partials to scratch; tiny final reduce. Deterministic.
// ---------------------------------------------------------------------------
__global__ __launch_bounds__(256) void k_bnpart(
    const float* __restrict__ pre, float* __restrict__ part) {
  const int b = blockIdx.x, c = threadIdx.x;
  const float* p0 = pre + (size_t)b * 128 * 256;
  float s = 0.f, s2 = 0.f;
  for (int r = 0; r < 128; ++r) {
    const float v = p0[(size_t)r * 256 + c];
    s += v; s2 += v * v;
  }
  part[b * 512 + c]       = s;
  part[b * 512 + 256 + c] = s2;
}

__global__ __launch_bounds__(256) void k_bnfinal(
    const float* __restrict__ part, float* __restrict__ st) {
  const int c = threadIdx.x;
  float s = 0.f, s2 = 0.f;
  for (int b = 0; b < 256; ++b) {
    s  += part[b * 512 + c];
    s2 += part[b * 512 + 256 + c];
  }
  st[c] = s; st[256 + c] = s2;
}

// ---------------------------------------------------------------------------
// bn_apply: out = relu(g*(pre-m)/sqrt(v+eps)+be), out-of-place.
// ---------------------------------------------------------------------------
__global__ __launch_bounds__(256) void k_bnapply(
    const float* __restrict__ pre, const float* __restrict__ st,
    const float* __restrict__ g, const float* __restrict__ be,
    float* __restrict__ out) {
  const int r = blockIdx.x, c = threadIdx.x;
  const float m = st[c] * (1.0f / 32768.0f);
  const float var = st[256 + c] * (1.0f / 32768.0f) - m * m;
  const float sc = g[c] * rsqrtf(var + 1e-5f);
  const float sh = be[c] - m * sc;
  const size_t i = (size_t)r * 256 + c;
  out[i] = fmaxf(pre[i] * sc + sh, 0.0f);
}

// ---------------------------------------------------------------------------
// head split-K GEMM stage 1: part[kb][64][128] = graph[:, kb*128:+128] @ Wm1-chunk
// 1024 blocks x 256 thr; k unrolled x4; deterministic partials (no atomics).
// ---------------------------------------------------------------------------
__global__ __launch_bounds__(256) void k_headgemm_p(
    const float* __restrict__ graph, const float* __restrict__ Wm1,
    float* __restrict__ part) {
  const int t = threadIdx.x;
  const int hg = t & 31;   // cols hg*4..+3
  const int bg = t >> 5;   // rows bg*8..+7
  float acc[8][4];
  #pragma unroll
  for (int i = 0; i < 8; ++i)
    #pragma unroll
    for (int j = 0; j < 4; ++j) acc[i][j] = 0.f;
  const int k0 = blockIdx.x * 128;
  for (int kk = 0; kk < 128; kk += 4) {
    const int k = k0 + kk;
    const float4 w0 = *(const float4*)(Wm1 + (size_t)(k + 0) * 128 + hg * 4);
    const float4 w1 = *(const float4*)(Wm1 + (size_t)(k + 1) * 128 + hg * 4);
    const float4 w2 = *(const float4*)(Wm1 + (size_t)(k + 2) * 128 + hg * 4);
    const float4 w3 = *(const float4*)(Wm1 + (size_t)(k + 3) * 128 + hg * 4);
    #pragma unroll
    for (int i = 0; i < 8; ++i) {
      const float4 a = *(const float4*)(graph + (size_t)(bg * 8 + i) * FEAT_ + k);
      acc[i][0] += a.x * w0.x; acc[i][1] += a.x * w0.y;
      acc[i][2] += a.x * w0.z; acc[i][3] += a.x * w0.w;
      acc[i][0] += a.y * w1.x; acc[i][1] += a.y * w1.y;
      acc[i][2] += a.y * w1.z; acc[i][3] += a.y * w1.w;
      acc[i][0] += a.z * w2.x; acc[i][1] += a.z * w2.y;
      acc[i][2] += a.z * w2.z; acc[i][3] += a.z * w2.w;
      acc[i][0] += a.w * w3.x; acc[i][1] += a.w * w3.y;
      acc[i][2] += a.w * w3.z; acc[i][3] += a.w * w3.w;
    }
  }
  float* pb = part + (size_t)blockIdx.x * 8192;
  #pragma unroll
  for (int i = 0; i < 8; ++i)
    *(float4*)(pb + (bg * 8 + i) * 128 + hg * 4) =
        make_float4(acc[i][0], acc[i][1], acc[i][2], acc[i][3]);
}

// ---------------------------------------------------------------------------
// head reduce stage A: part2[jg][o] = sum_{j=jg*128..+127} part[j][o]
// grid (32 og, 8 jg) x 256 thr; coalesced, deterministic.
// ---------------------------------------------------------------------------
__global__ __launch_bounds__(256) void k_headredA(
    const float* __restrict__ part, float* __restrict__ part2) {
  const int o = blockIdx.x * 256 + threadIdx.x;
  const int jg = blockIdx.y;
  float s = 0.f;
  for (int j = jg * 128; j < jg * 128 + 128; ++j) s += part[(size_t)j * 8192 + o];
  part2[(size_t)jg * 8192 + o] = s;
}

// head reduce stage B: z1[o] = sum_{jg<8} part2[jg][o]
__global__ __launch_bounds__(256) void k_headredB(
    const float* __restrict__ part2, float* __restrict__ z1) {
  const int o = blockIdx.x * 256 + threadIdx.x;
  float s = 0.f;
  #pragma unroll
  for (int jg = 0; jg < 8; ++jg) s += part2[(size_t)jg * 8192 + o];
  z1[o] = s;
}

// ---------------------------------------------------------------------------
// head BN over batch (J features) + ReLU
// ---------------------------------------------------------------------------
template <int J>
__global__ __launch_bounds__(64) void k_headbn(
    const float* __restrict__ z, const float* __restrict__ g,
    const float* __restrict__ be, float* __restrict__ zr) {
  __shared__ float rs[64], rs2[64];
  const int j = blockIdx.x, b = threadIdx.x;
  const float v = z[b * J + j];
  rs[b] = v; rs2[b] = v * v; __syncthreads();
  for (int s = 32; s; s >>= 1) {
    if (b < s) { rs[b] += rs[b + s]; rs2[b] += rs2[b + s]; }
    __syncthreads();
  }
  const float m = rs[0] * (1.0f / 64.0f);
  const float var = rs2[0] * (1.0f / 64.0f) - m * m;
  const float sc = g[j] * rsqrtf(var + 1e-5f);
  const float sh = be[j] - m * sc;
  zr[b * J + j] = fmaxf(v * sc + sh, 0.0f);
}

__global__ __launch_bounds__(64) void k_headmm2(
    const float* __restrict__ zr1, const float* __restrict__ Wm2,
    float* __restrict__ z2) {
  const int b = blockIdx.x, j = threadIdx.x;
  float acc = 0.f;
  for (int k = 0; k < 128; ++k) acc += zr1[b * 128 + k] * Wm2[k * 64 + j];
  z2[b * 64 + j] = acc;
}

__global__ __launch_bounds__(128) void k_headout(
    const float* __restrict__ zr2, const float* __restrict__ Wm3,
    const float* __restrict__ bm3, float* __restrict__ out) {
  const int t = threadIdx.x;
  const int b = t >> 1, c = t & 1;
  float s = bm3[c];
  for (int k = 0; k < 64; ++k) s += zr2[b * 64 + k] * Wm3[k * 2 + c];
  out[t] = s;
}

// ---------------------------------------------------------------------------
extern "C" void kernel_launch(void* const* d_in, const int* in_sizes, int n_in,
                              void* d_out, int out_size, void* d_ws, size_t ws_size,
                              hipStream_t stream) {
  (void)in_sizes; (void)n_in; (void)out_size; (void)ws_size;
  const float* x    = (const float*)d_in[0];
  const float* mask = (const float*)d_in[1];
  const float* W1   = (const float*)d_in[2];
  const float* b1   = (const float*)d_in[3];
  const float* g1   = (const float*)d_in[4];
  const float* be1  = (const float*)d_in[5];
  const float* W2   = (const float*)d_in[6];
  const float* b2   = (const float*)d_in[7];
  const float* g2   = (const float*)d_in[8];
  const float* be2  = (const float*)d_in[9];
  const float* Wm1  = (const float*)d_in[10];
  // d_in[11] = bm1 (zeros; cancels under BN)
  const float* gm1  = (const float*)d_in[12];
  const float* bem1 = (const float*)d_in[13];
  const float* Wm2  = (const float*)d_in[14];
  // d_in[15] = bm2 (zeros; cancels under BN)
  const float* gm2  = (const float*)d_in[16];
  const float* bem2 = (const float*)d_in[17];
  const float* Wm3  = (const float*)d_in[18];
  const float* bm3  = (const float*)d_in[19];

  // workspace (floats), same layout as verified previously (117.67 MB)
  float* ws   = (float*)d_ws;
  float* T1   = ws;                 // 8,388,608 : xn -> h1 -> h2 (= graph)
  float* An   = T1 + 8388608;       // 4,194,304
  float* T2   = An + 4194304;       // 8,388,608 : XW1 -> XW2 -> head partials
  float* T3   = T2 + 8388608;       // 8,388,608 : pre1 -> pre2 -> head part2
  float* z1   = T3 + 8388608;       // 8,192
  float* dinv = z1 + 8192;          // 32,768 (unused, kept for layout)
  float* st1  = dinv + 32768;       // 512
  float* st2  = st1 + 512;          // 512
  float* zr1  = st2 + 512;          // 8,192
  float* z2   = zr1 + 8192;         // 4,096
  float* zr2  = z2 + 4096;          // 4,096

  // edges / An (fused: sim + deg + normalize)
  k_xn<<<8192, 256, 0, stream>>>(x, T1);
  k_simfused<<<256, 256, 0, stream>>>(T1, mask, An);

  // layer 1
  k_gemm_t<<<dim3(256, 2), 256, 0, stream>>>(x, W1, b1, T2);
  k_bmm_t<<<dim3(256, 2), 256, 0, stream>>>(An, T2, T3);
  k_bnpart<<<256, 256, 0, stream>>>(T3, T2);     // T2 free after bmm
  k_bnfinal<<<1, 256, 0, stream>>>(T2, st1);
  k_bnapply<<<32768, 256, 0, stream>>>(T3, st1, g1, be1, T1);   // h1

  // layer 2
  k_gemm_t<<<dim3(256, 2), 256, 0, stream>>>(T1, W2, b2, T2);
  k_bmm_t<<<dim3(256, 2), 256, 0, stream>>>(An, T2, T3);
  k_bnpart<<<256, 256, 0, stream>>>(T3, T2);
  k_bnfinal<<<1, 256, 0, stream>>>(T2, st2);
  k_bnapply<<<32768, 256, 0, stream>>>(T3, st2, g2, be2, T1);   // h2

  // head: split-K partials (T2) -> 2-stage deterministic reduce (T3) -> z1
  k_headgemm_p<<<1024, 256, 0, stream>>>(T1, Wm1, T2);
  k_headredA<<<dim3(32, 8), 256, 0, stream>>>(T2, T3);
  k_headredB<<<32, 256, 0, stream>>>(T3, z1);
  k_headbn<128><<<128, 64, 0, stream>>>(z1, gm1, bem1, zr1);
  k_headmm2<<<64, 64, 0, stream>>>(zr1, Wm2, z2);
  k_headbn<64><<<64, 64, 0, stream>>>(z2, gm2, bem2, zr2);
  k_headout<<<1, 128, 0, stream>>>(zr2, Wm3, bm3, (float*)d_out);
}

// Round 5
// 518.788 us; speedup vs baseline: 5.0093x; 1.0716x over previous
//
#include <hip/hip_runtime.h>
#include <cstdint>
#include <cstddef>

// Shapes (fixed): B=64, N=4, P=128, d=h=256, totP=512, feat=131072
#define P_    128
#define H_    256
#define FEAT_ 131072

// ---------------------------------------------------------------------------
// xn: row-normalize x. 8192 blocks x 256 thr; one wave per row, float4 loads,
// wave-shuffle reduce.
// ---------------------------------------------------------------------------
__global__ __launch_bounds__(256) void k_xn(
    const float* __restrict__ x, float* __restrict__ xn) {
  const int t = threadIdx.x;
  const int lane = t & 63;
  const int row = blockIdx.x * 4 + (t >> 6);
  const float* xr = x + (size_t)row * 256;
  const float4 v = *(const float4*)(xr + lane * 4);
  float ss = v.x * v.x + v.y * v.y + v.z * v.z + v.w * v.w;
  #pragma unroll
  for (int s = 32; s; s >>= 1) ss += __shfl_xor(ss, s, 64);
  const float inv = 1.0f / fmaxf(sqrtf(ss), 1e-12f);
  *(float4*)(xn + (size_t)row * 256 + lane * 4) =
      make_float4(v.x * inv, v.y * inv, v.z * inv, v.w * inv);
}

// ---------------------------------------------------------------------------
// Fused sim + deg + sym-normalize. One block per blk (256 blocks, 256 thr).
// ---------------------------------------------------------------------------
__global__ __launch_bounds__(256) void k_simfused(
    const float* __restrict__ xn, const float* __restrict__ mask,
    float* __restrict__ An) {
  __shared__ float Xs[16][128];      // [k][row], chunk of K
  __shared__ float red[128][17];     // row partial sums
  __shared__ float dinv_s[128];
  const int blk = blockIdx.x;
  const int t = threadIdx.x;
  const int tp = t >> 4, tq = t & 15;   // rows tp*8..+7, cols tq*8..+7
  const float* Xb = xn + (size_t)blk * (128 * 256);

  float v[8][8];
  #pragma unroll
  for (int i = 0; i < 8; ++i)
    #pragma unroll
    for (int j = 0; j < 8; ++j) v[i][j] = 0.f;

  for (int kc = 0; kc < 16; ++kc) {
    __syncthreads();
    #pragma unroll
    for (int l = 0; l < 2; ++l) {
      const int f = t + 256 * l;
      const int row = f >> 2, k4 = (f & 3) * 4;
      const float4 x4 = *(const float4*)(Xb + (size_t)row * 256 + kc * 16 + k4);
      Xs[k4 + 0][row] = x4.x;
      Xs[k4 + 1][row] = x4.y;
      Xs[k4 + 2][row] = x4.z;
      Xs[k4 + 3][row] = x4.w;
    }
    __syncthreads();
    #pragma unroll
    for (int k = 0; k < 16; ++k) {
      const float4 a0 = *(const float4*)&Xs[k][tp * 8];
      const float4 a1 = *(const float4*)&Xs[k][tp * 8 + 4];
      const float4 b0 = *(const float4*)&Xs[k][tq * 8];
      const float4 b1 = *(const float4*)&Xs[k][tq * 8 + 4];
      const float a[8] = {a0.x, a0.y, a0.z, a0.w, a1.x, a1.y, a1.z, a1.w};
      const float b[8] = {b0.x, b0.y, b0.z, b0.w, b1.x, b1.y, b1.z, b1.w};
      #pragma unroll
      for (int i = 0; i < 8; ++i)
        #pragma unroll
        for (int j = 0; j < 8; ++j) v[i][j] += a[i] * b[j];
    }
  }

  #pragma unroll
  for (int i = 0; i < 8; ++i) {
    const int r = tp * 8 + i;
    const float4 m0 = *(const float4*)(mask + r * 128 + tq * 8);
    const float4 m1 = *(const float4*)(mask + r * 128 + tq * 8 + 4);
    const float mm[8] = {m0.x, m0.y, m0.z, m0.w, m1.x, m1.y, m1.z, m1.w};
    float s = 0.f;
    #pragma unroll
    for (int j = 0; j < 8; ++j) {
      const int c = tq * 8 + j;
      const float vv = (r == c) ? 0.0f : (v[i][j] + 1.0f) * 0.5f * mm[j];
      v[i][j] = vv;
      s += vv;
    }
    red[r][tq] = s;
  }
  __syncthreads();
  if (t < 128) {
    float sm = 0.f;
    #pragma unroll
    for (int u = 0; u < 16; ++u) sm += red[t][u];
    const float deg = 1.0f + sm;
    dinv_s[t] = (deg > 0.0f) ? rsqrtf(fmaxf(deg, 1e-12f)) : 0.0f;
  }
  __syncthreads();

  float dq[8];
  #pragma unroll
  for (int j = 0; j < 8; ++j) dq[j] = dinv_s[tq * 8 + j];
  float* Ab = An + (size_t)blk * 16384;
  #pragma unroll
  for (int i = 0; i < 8; ++i) {
    const int r = tp * 8 + i;
    const float dp = dinv_s[r];
    float o[8];
    #pragma unroll
    for (int j = 0; j < 8; ++j) {
      const int c = tq * 8 + j;
      o[j] = (r == c) ? dp * dq[j] : v[i][j] * dp * dq[j];
    }
    *(float4*)(Ab + (size_t)r * 128 + tq * 8)     = make_float4(o[0], o[1], o[2], o[3]);
    *(float4*)(Ab + (size_t)r * 128 + tq * 8 + 4) = make_float4(o[4], o[5], o[6], o[7]);
  }
}

// ---------------------------------------------------------------------------
// Tiled GEMM (layer 1): out[32768][256] = A @ W + bias. Grid (256,2).
// ---------------------------------------------------------------------------
__global__ __launch_bounds__(256) void k_gemm_t(
    const float* __restrict__ A, const float* __restrict__ W,
    const float* __restrict__ bias, float* __restrict__ out) {
  __shared__ float As[16][128];   // [k][row]
  __shared__ float Ws[16][128];   // [k][col]
  const int rb = blockIdx.x, cb = blockIdx.y;
  const int t = threadIdx.x, tp = t >> 4, tq = t & 15;
  const int m0 = rb * 128, c0 = cb * 128;

  float acc[8][8];
  #pragma unroll
  for (int j = 0; j < 8; ++j) {
    const float bj = bias[c0 + tq * 8 + j];
    #pragma unroll
    for (int i = 0; i < 8; ++i) acc[i][j] = bj;
  }

  for (int kc = 0; kc < 16; ++kc) {
    __syncthreads();
    #pragma unroll
    for (int l = 0; l < 2; ++l) {
      const int f = t + 256 * l;
      const int row = f >> 2, k4 = (f & 3) * 4;
      const float4 a4 = *(const float4*)(A + (size_t)(m0 + row) * 256 + kc * 16 + k4);
      As[k4 + 0][row] = a4.x;
      As[k4 + 1][row] = a4.y;
      As[k4 + 2][row] = a4.z;
      As[k4 + 3][row] = a4.w;
    }
    #pragma unroll
    for (int l = 0; l < 2; ++l) {
      const int f = t + 256 * l;
      const int k = f >> 5, c4 = (f & 31) * 4;
      const float4 w4 = *(const float4*)(W + (size_t)(kc * 16 + k) * 256 + c0 + c4);
      *(float4*)&Ws[k][c4] = w4;
    }
    __syncthreads();
    #pragma unroll
    for (int k = 0; k < 16; ++k) {
      const float4 a0 = *(const float4*)&As[k][tp * 8];
      const float4 a1 = *(const float4*)&As[k][tp * 8 + 4];
      const float4 w0 = *(const float4*)&Ws[k][tq * 8];
      const float4 w1 = *(const float4*)&Ws[k][tq * 8 + 4];
      const float a[8] = {a0.x, a0.y, a0.z, a0.w, a1.x, a1.y, a1.z, a1.w};
      const float w[8] = {w0.x, w0.y, w0.z, w0.w, w1.x, w1.y, w1.z, w1.w};
      #pragma unroll
      for (int i = 0; i < 8; ++i)
        #pragma unroll
        for (int j = 0; j < 8; ++j) acc[i][j] += a[i] * w[j];
    }
  }

  #pragma unroll
  for (int i = 0; i < 8; ++i) {
    float* orow = out + (size_t)(m0 + tp * 8 + i) * 256 + c0 + tq * 8;
    *(float4*)(orow)     = make_float4(acc[i][0], acc[i][1], acc[i][2], acc[i][3]);
    *(float4*)(orow + 4) = make_float4(acc[i][4], acc[i][5], acc[i][6], acc[i][7]);
  }
}

// ---------------------------------------------------------------------------
// Tiled GEMM (layer 2) with fused BN+ReLU on the A operand at staging time:
// a = fmax(pre*sc[col] + sh[col], 0). scsh: [0..255]=sc, [256..511]=sh.
// ---------------------------------------------------------------------------
__global__ __launch_bounds__(256) void k_gemmbn_t(
    const float* __restrict__ A, const float* __restrict__ scsh,
    const float* __restrict__ W, const float* __restrict__ bias,
    float* __restrict__ out) {
  __shared__ float As[16][128];
  __shared__ float Ws[16][128];
  const int rb = blockIdx.x, cb = blockIdx.y;
  const int t = threadIdx.x, tp = t >> 4, tq = t & 15;
  const int m0 = rb * 128, c0 = cb * 128;

  float acc[8][8];
  #pragma unroll
  for (int j = 0; j < 8; ++j) {
    const float bj = bias[c0 + tq * 8 + j];
    #pragma unroll
    for (int i = 0; i < 8; ++i) acc[i][j] = bj;
  }

  for (int kc = 0; kc < 16; ++kc) {
    __syncthreads();
    #pragma unroll
    for (int l = 0; l < 2; ++l) {
      const int f = t + 256 * l;
      const int row = f >> 2, k4 = (f & 3) * 4;
      const int col = kc * 16 + k4;                 // channel of h1
      const float4 a4 = *(const float4*)(A + (size_t)(m0 + row) * 256 + col);
      const float4 sc = *(const float4*)(scsh + col);
      const float4 sh = *(const float4*)(scsh + 256 + col);
      As[k4 + 0][row] = fmaxf(a4.x * sc.x + sh.x, 0.0f);
      As[k4 + 1][row] = fmaxf(a4.y * sc.y + sh.y, 0.0f);
      As[k4 + 2][row] = fmaxf(a4.z * sc.z + sh.z, 0.0f);
      As[k4 + 3][row] = fmaxf(a4.w * sc.w + sh.w, 0.0f);
    }
    #pragma unroll
    for (int l = 0; l < 2; ++l) {
      const int f = t + 256 * l;
      const int k = f >> 5, c4 = (f & 31) * 4;
      const float4 w4 = *(const float4*)(W + (size_t)(kc * 16 + k) * 256 + c0 + c4);
      *(float4*)&Ws[k][c4] = w4;
    }
    __syncthreads();
    #pragma unroll
    for (int k = 0; k < 16; ++k) {
      const float4 a0 = *(const float4*)&As[k][tp * 8];
      const float4 a1 = *(const float4*)&As[k][tp * 8 + 4];
      const float4 w0 = *(const float4*)&Ws[k][tq * 8];
      const float4 w1 = *(const float4*)&Ws[k][tq * 8 + 4];
      const float a[8] = {a0.x, a0.y, a0.z, a0.w, a1.x, a1.y, a1.z, a1.w};
      const float w[8] = {w0.x, w0.y, w0.z, w0.w, w1.x, w1.y, w1.z, w1.w};
      #pragma unroll
      for (int i = 0; i < 8; ++i)
        #pragma unroll
        for (int j = 0; j < 8; ++j) acc[i][j] += a[i] * w[j];
    }
  }

  #pragma unroll
  for (int i = 0; i < 8; ++i) {
    float* orow = out + (size_t)(m0 + tp * 8 + i) * 256 + c0 + tq * 8;
    *(float4*)(orow)     = make_float4(acc[i][0], acc[i][1], acc[i][2], acc[i][3]);
    *(float4*)(orow + 4) = make_float4(acc[i][4], acc[i][5], acc[i][6], acc[i][7]);
  }
}

// ---------------------------------------------------------------------------
// Tiled bmm + fused BN-stat partials. Grid (256 blks x 2 colblocks).
// Each block reduces its 128x128 tile to per-column sum/sumsq (LDS tree) and
// writes part[(blk*2+cb)*256 + {lc | 128+lc}]. Deterministic.
// ---------------------------------------------------------------------------
__global__ __launch_bounds__(256) void k_bmmst(
    const float* __restrict__ An, const float* __restrict__ XW,
    float* __restrict__ out, float* __restrict__ part) {
  __shared__ float As[16][128];   // [q][p]
  __shared__ float Ws[16][128];   // [q][c]
  __shared__ float rs[16][128];   // col-sum partial per tp group
  __shared__ float rq[16][128];   // col-sumsq partial
  const int blk = blockIdx.x, cb = blockIdx.y;
  const int t = threadIdx.x, tp = t >> 4, tq = t & 15;
  const float* Ab = An + (size_t)blk * 16384;
  const float* Xb = XW + (size_t)blk * (128 * 256);

  float acc[8][8];
  #pragma unroll
  for (int i = 0; i < 8; ++i)
    #pragma unroll
    for (int j = 0; j < 8; ++j) acc[i][j] = 0.f;

  for (int kc = 0; kc < 8; ++kc) {
    __syncthreads();
    #pragma unroll
    for (int l = 0; l < 2; ++l) {
      const int f = t + 256 * l;
      const int row = f >> 2, k4 = (f & 3) * 4;
      const float4 a4 = *(const float4*)(Ab + (size_t)row * 128 + kc * 16 + k4);
      As[k4 + 0][row] = a4.x;
      As[k4 + 1][row] = a4.y;
      As[k4 + 2][row] = a4.z;
      As[k4 + 3][row] = a4.w;
    }
    #pragma unroll
    for (int l = 0; l < 2; ++l) {
      const int f = t + 256 * l;
      const int k = f >> 5, c4 = (f & 31) * 4;
      const float4 w4 = *(const float4*)(Xb + (size_t)(kc * 16 + k) * 256 + cb * 128 + c4);
      *(float4*)&Ws[k][c4] = w4;
    }
    __syncthreads();
    #pragma unroll
    for (int k = 0; k < 16; ++k) {
      const float4 a0 = *(const float4*)&As[k][tp * 8];
      const float4 a1 = *(const float4*)&As[k][tp * 8 + 4];
      const float4 w0 = *(const float4*)&Ws[k][tq * 8];
      const float4 w1 = *(const float4*)&Ws[k][tq * 8 + 4];
      const float a[8] = {a0.x, a0.y, a0.z, a0.w, a1.x, a1.y, a1.z, a1.w};
      const float w[8] = {w0.x, w0.y, w0.z, w0.w, w1.x, w1.y, w1.z, w1.w};
      #pragma unroll
      for (int i = 0; i < 8; ++i)
        #pragma unroll
        for (int j = 0; j < 8; ++j) acc[i][j] += a[i] * w[j];
    }
  }

  // per-thread column partials (8 rows) -> LDS -> 128-thread final
  #pragma unroll
  for (int j = 0; j < 8; ++j) {
    float cs = 0.f, cq = 0.f;
    #pragma unroll
    for (int i = 0; i < 8; ++i) { cs += acc[i][j]; cq += acc[i][j] * acc[i][j]; }
    rs[tp][tq * 8 + j] = cs;
    rq[tp][tq * 8 + j] = cq;
  }
  __syncthreads();
  if (t < 128) {
    float s = 0.f, q = 0.f;
    #pragma unroll
    for (int u = 0; u < 16; ++u) { s += rs[u][t]; q += rq[u][t]; }
    const int base = (blk * 2 + cb) * 256;
    part[base + t]       = s;
    part[base + 128 + t] = q;
  }

  #pragma unroll
  for (int i = 0; i < 8; ++i) {
    float* orow = out + (size_t)(blk * 128 + tp * 8 + i) * 256 + cb * 128 + tq * 8;
    *(float4*)(orow)     = make_float4(acc[i][0], acc[i][1], acc[i][2], acc[i][3]);
    *(float4*)(orow + 4) = make_float4(acc[i][4], acc[i][5], acc[i][6], acc[i][7]);
  }
}

// ---------------------------------------------------------------------------
// bn final: st[c] = sum over 512 block-partials; fixed order (deterministic).
// ---------------------------------------------------------------------------
__global__ __launch_bounds__(256) void k_bnfinal2(
    const float* __restrict__ part, float* __restrict__ st) {
  const int c = threadIdx.x;
  const int cb = c >> 7, lc = c & 127;
  float s = 0.f, q = 0.f;
  for (int blk = 0; blk < 256; ++blk) {
    const float* pb = part + (size_t)(blk * 2 + cb) * 256;
    s += pb[lc];
    q += pb[128 + lc];
  }
  st[c] = s; st[256 + c] = q;
}

// scsh[c] = g*rsqrt(var+eps) ; scsh[256+c] = be - m*sc
__global__ __launch_bounds__(256) void k_scsh(
    const float* __restrict__ st, const float* __restrict__ g,
    const float* __restrict__ be, float* __restrict__ scsh) {
  const int c = threadIdx.x;
  const float m = st[c] * (1.0f / 32768.0f);
  const float var = st[256 + c] * (1.0f / 32768.0f) - m * m;
  const float sc = g[c] * rsqrtf(var + 1e-5f);
  scsh[c] = sc;
  scsh[256 + c] = be[c] - m * sc;
}

// ---------------------------------------------------------------------------
// head split-K GEMM stage 1 with fused BN+ReLU on graph loads.
// 2048 blocks (K-chunk 64) x 256 thr. Partials: blocks <1024 -> partA,
// >=1024 -> partB (each 1024*8192 floats). Deterministic.
// ---------------------------------------------------------------------------
__global__ __launch_bounds__(256) void k_headgemm_p(
    const float* __restrict__ pre2, const float* __restrict__ scsh,
    const float* __restrict__ Wm1, float* __restrict__ partA,
    float* __restrict__ partB) {
  const int t = threadIdx.x;
  const int hg = t & 31;   // cols hg*4..+3
  const int bg = t >> 5;   // rows bg*8..+7
  float acc[8][4];
  #pragma unroll
  for (int i = 0; i < 8; ++i)
    #pragma unroll
    for (int j = 0; j < 4; ++j) acc[i][j] = 0.f;
  const int bid = blockIdx.x;
  const int k0 = bid * 64;
  const int cbase = k0 & 255;           // channel base (no wrap within chunk)
  for (int kk = 0; kk < 64; kk += 4) {
    const int k = k0 + kk;
    const int ch = cbase + kk;
    const float4 sc4 = *(const float4*)(scsh + ch);
    const float4 sh4 = *(const float4*)(scsh + 256 + ch);
    const float4 w0 = *(const float4*)(Wm1 + (size_t)(k + 0) * 128 + hg * 4);
    const float4 w1 = *(const float4*)(Wm1 + (size_t)(k + 1) * 128 + hg * 4);
    const float4 w2 = *(const float4*)(Wm1 + (size_t)(k + 2) * 128 + hg * 4);
    const float4 w3 = *(const float4*)(Wm1 + (size_t)(k + 3) * 128 + hg * 4);
    #pragma unroll
    for (int i = 0; i < 8; ++i) {
      const float4 p = *(const float4*)(pre2 + (size_t)(bg * 8 + i) * FEAT_ + k);
      const float ax = fmaxf(p.x * sc4.x + sh4.x, 0.0f);
      const float ay = fmaxf(p.y * sc4.y + sh4.y, 0.0f);
      const float az = fmaxf(p.z * sc4.z + sh4.z, 0.0f);
      const float aw = fmaxf(p.w * sc4.w + sh4.w, 0.0f);
      acc[i][0] += ax * w0.x; acc[i][1] += ax * w0.y;
      acc[i][2] += ax * w0.z; acc[i][3] += ax * w0.w;
      acc[i][0] += ay * w1.x; acc[i][1] += ay * w1.y;
      acc[i][2] += ay * w1.z; acc[i][3] += ay * w1.w;
      acc[i][0] += az * w2.x; acc[i][1] += az * w2.y;
      acc[i][2] += az * w2.z; acc[i][3] += az * w2.w;
      acc[i][0] += aw * w3.x; acc[i][1] += aw * w3.y;
      acc[i][2] += aw * w3.z; acc[i][3] += aw * w3.w;
    }
  }
  float* pb = (bid < 1024) ? (partA + (size_t)bid * 8192)
                           : (partB + (size_t)(bid - 1024) * 8192);
  #pragma unroll
  for (int i = 0; i < 8; ++i)
    *(float4*)(pb + (bg * 8 + i) * 128 + hg * 4) =
        make_float4(acc[i][0], acc[i][1], acc[i][2], acc[i][3]);
}

// ---------------------------------------------------------------------------
// head reduce stage A: part2[jg][o] = sum of 128 consecutive partials.
// grid (32 og, 16 jg) x 256 thr; jg<8 reads partA, else partB.
// ---------------------------------------------------------------------------
__global__ __launch_bounds__(256) void k_headredA(
    const float* __restrict__ partA, const float* __restrict__ partB,
    float* __restrict__ part2) {
  const int o = blockIdx.x * 256 + threadIdx.x;
  const int jg = blockIdx.y;
  const float* base = (jg < 8) ? (partA + (size_t)jg * 128 * 8192)
                               : (partB + (size_t)(jg - 8) * 128 * 8192);
  float s = 0.f;
  for (int j = 0; j < 128; ++j) s += base[(size_t)j * 8192 + o];
  part2[(size_t)jg * 8192 + o] = s;
}

// head reduce stage B: z1[o] = sum_{jg<16} part2[jg][o]
__global__ __launch_bounds__(256) void k_headredB(
    const float* __restrict__ part2, float* __restrict__ z1) {
  const int o = blockIdx.x * 256 + threadIdx.x;
  float s = 0.f;
  #pragma unroll
  for (int jg = 0; jg < 16; ++jg) s += part2[(size_t)jg * 8192 + o];
  z1[o] = s;
}

// ---------------------------------------------------------------------------
// head BN over batch (J features) + ReLU
// ---------------------------------------------------------------------------
template <int J>
__global__ __launch_bounds__(64) void k_headbn(
    const float* __restrict__ z, const float* __restrict__ g,
    const float* __restrict__ be, float* __restrict__ zr) {
  __shared__ float rs[64], rs2[64];
  const int j = blockIdx.x, b = threadIdx.x;
  const float v = z[b * J + j];
  rs[b] = v; rs2[b] = v * v; __syncthreads();
  for (int s = 32; s; s >>= 1) {
    if (b < s) { rs[b] += rs[b + s]; rs2[b] += rs2[b + s]; }
    __syncthreads();
  }
  const float m = rs[0] * (1.0f / 64.0f);
  const float var = rs2[0] * (1.0f / 64.0f) - m * m;
  const float sc = g[j] * rsqrtf(var + 1e-5f);
  const float sh = be[j] - m * sc;
  zr[b * J + j] = fmaxf(v * sc + sh, 0.0f);
}

__global__ __launch_bounds__(64) void k_headmm2(
    const float* __restrict__ zr1, const float* __restrict__ Wm2,
    float* __restrict__ z2) {
  const int b = blockIdx.x, j = threadIdx.x;
  float acc = 0.f;
  for (int k = 0; k < 128; ++k) acc += zr1[b * 128 + k] * Wm2[k * 64 + j];
  z2[b * 64 + j] = acc;
}

__global__ __launch_bounds__(128) void k_headout(
    const float* __restrict__ zr2, const float* __restrict__ Wm3,
    const float* __restrict__ bm3, float* __restrict__ out) {
  const int t = threadIdx.x;
  const int b = t >> 1, c = t & 1;
  float s = bm3[c];
  for (int k = 0; k < 64; ++k) s += zr2[b * 64 + k] * Wm3[k * 2 + c];
  out[t] = s;
}

// ---------------------------------------------------------------------------
extern "C" void kernel_launch(void* const* d_in, const int* in_sizes, int n_in,
                              void* d_out, int out_size, void* d_ws, size_t ws_size,
                              hipStream_t stream) {
  (void)in_sizes; (void)n_in; (void)out_size; (void)ws_size;
  const float* x    = (const float*)d_in[0];
  const float* mask = (const float*)d_in[1];
  const float* W1   = (const float*)d_in[2];
  const float* b1   = (const float*)d_in[3];
  const float* g1   = (const float*)d_in[4];
  const float* be1  = (const float*)d_in[5];
  const float* W2   = (const float*)d_in[6];
  const float* b2   = (const float*)d_in[7];
  const float* g2   = (const float*)d_in[8];
  const float* be2  = (const float*)d_in[9];
  const float* Wm1  = (const float*)d_in[10];
  // d_in[11] = bm1 (zeros; cancels under BN)
  const float* gm1  = (const float*)d_in[12];
  const float* bem1 = (const float*)d_in[13];
  const float* Wm2  = (const float*)d_in[14];
  // d_in[15] = bm2 (zeros; cancels under BN)
  const float* gm2  = (const float*)d_in[16];
  const float* bem2 = (const float*)d_in[17];
  const float* Wm3  = (const float*)d_in[18];
  const float* bm3  = (const float*)d_in[19];

  // workspace (floats), same extent as verified previously (117.67 MB)
  float* ws   = (float*)d_ws;
  float* T1   = ws;                 // 8,388,608 : xn -> bn partials -> head partB
  float* An   = T1 + 8388608;       // 4,194,304 : An -> head part2
  float* T2   = An + 4194304;       // 8,388,608 : XW1 -> XW2 -> head partA
  float* T3   = T2 + 8388608;       // 8,388,608 : pre1 -> pre2
  float* z1   = T3 + 8388608;       // 8,192
  float* dinv = z1 + 8192;          // 32,768 : scsh1 at +0, scsh2 at +512
  float* st1  = dinv + 32768;       // 512
  float* st2  = st1 + 512;          // 512
  float* zr1  = st2 + 512;          // 8,192
  float* z2   = zr1 + 8192;         // 4,096
  float* zr2  = z2 + 4096;          // 4,096

  float* scsh1 = dinv;
  float* scsh2 = dinv + 512;

  // edges / An (fused: sim + deg + normalize)
  k_xn<<<8192, 256, 0, stream>>>(x, T1);
  k_simfused<<<256, 256, 0, stream>>>(T1, mask, An);

  // layer 1: pre1 = An @ (x@W1+b1); stats fused into bmm
  k_gemm_t<<<dim3(256, 2), 256, 0, stream>>>(x, W1, b1, T2);
  k_bmmst<<<dim3(256, 2), 256, 0, stream>>>(An, T2, T3, T1);   // T1: xn dead
  k_bnfinal2<<<1, 256, 0, stream>>>(T1, st1);
  k_scsh<<<1, 256, 0, stream>>>(st1, g1, be1, scsh1);

  // layer 2: pre2 = An @ (relu(bn(pre1))@W2+b2); bn fused into A-staging
  k_gemmbn_t<<<dim3(256, 2), 256, 0, stream>>>(T3, scsh1, W2, b2, T2);
  k_bmmst<<<dim3(256, 2), 256, 0, stream>>>(An, T2, T3, T1);
  k_bnfinal2<<<1, 256, 0, stream>>>(T1, st2);
  k_scsh<<<1, 256, 0, stream>>>(st2, g2, be2, scsh2);

  // head: z1 = relu(bn(pre2)) @ Wm1, split-K 2048 + 2-stage reduce
  k_headgemm_p<<<2048, 256, 0, stream>>>(T3, scsh2, Wm1, T2, T1);
  k_headredA<<<dim3(32, 16), 256, 0, stream>>>(T2, T1, An);
  k_headredB<<<32, 256, 0, stream>>>(An, z1);
  k_headbn<128><<<128, 64, 0, stream>>>(z1, gm1, bem1, zr1);
  k_headmm2<<<64, 64, 0, stream>>>(zr1, Wm2, z2);
  k_headbn<64><<<64, 64, 0, stream>>>(z2, gm2, bem2, zr2);
  k_headout<<<1, 128, 0, stream>>>(zr2, Wm3, bm3, (float*)d_out);
}

// Round 6
// 458.140 us; speedup vs baseline: 5.6724x; 1.1324x over previous
//
#include <hip/hip_runtime.h>
#include <cstdint>
#include <cstddef>

// Shapes (fixed): B=64, N=4, P=128, d=h=256, totP=512, feat=131072
#define P_    128
#define H_    256
#define FEAT_ 131072

// ---------------------------------------------------------------------------
// xn: row-normalize x. 8192 blocks x 256 thr; one wave per row, float4 loads,
// wave-shuffle reduce.
// ---------------------------------------------------------------------------
__global__ __launch_bounds__(256) void k_xn(
    const float* __restrict__ x, float* __restrict__ xn) {
  const int t = threadIdx.x;
  const int lane = t & 63;
  const int row = blockIdx.x * 4 + (t >> 6);
  const float* xr = x + (size_t)row * 256;
  const float4 v = *(const float4*)(xr + lane * 4);
  float ss = v.x * v.x + v.y * v.y + v.z * v.z + v.w * v.w;
  #pragma unroll
  for (int s = 32; s; s >>= 1) ss += __shfl_xor(ss, s, 64);
  const float inv = 1.0f / fmaxf(sqrtf(ss), 1e-12f);
  *(float4*)(xn + (size_t)row * 256 + lane * 4) =
      make_float4(v.x * inv, v.y * inv, v.z * inv, v.w * inv);
}

// ---------------------------------------------------------------------------
// Fused sim + deg + sym-normalize. One block per blk (256 blocks, 256 thr).
// ---------------------------------------------------------------------------
__global__ __launch_bounds__(256) void k_simfused(
    const float* __restrict__ xn, const float* __restrict__ mask,
    float* __restrict__ An) {
  __shared__ float Xs[16][128];      // [k][row], chunk of K
  __shared__ float red[128][17];     // row partial sums
  __shared__ float dinv_s[128];
  const int blk = blockIdx.x;
  const int t = threadIdx.x;
  const int tp = t >> 4, tq = t & 15;   // rows tp*8..+7, cols tq*8..+7
  const float* Xb = xn + (size_t)blk * (128 * 256);

  float v[8][8];
  #pragma unroll
  for (int i = 0; i < 8; ++i)
    #pragma unroll
    for (int j = 0; j < 8; ++j) v[i][j] = 0.f;

  for (int kc = 0; kc < 16; ++kc) {
    __syncthreads();
    #pragma unroll
    for (int l = 0; l < 2; ++l) {
      const int f = t + 256 * l;
      const int row = f >> 2, k4 = (f & 3) * 4;
      const float4 x4 = *(const float4*)(Xb + (size_t)row * 256 + kc * 16 + k4);
      Xs[k4 + 0][row] = x4.x;
      Xs[k4 + 1][row] = x4.y;
      Xs[k4 + 2][row] = x4.z;
      Xs[k4 + 3][row] = x4.w;
    }
    __syncthreads();
    #pragma unroll
    for (int k = 0; k < 16; ++k) {
      const float4 a0 = *(const float4*)&Xs[k][tp * 8];
      const float4 a1 = *(const float4*)&Xs[k][tp * 8 + 4];
      const float4 b0 = *(const float4*)&Xs[k][tq * 8];
      const float4 b1 = *(const float4*)&Xs[k][tq * 8 + 4];
      const float a[8] = {a0.x, a0.y, a0.z, a0.w, a1.x, a1.y, a1.z, a1.w};
      const float b[8] = {b0.x, b0.y, b0.z, b0.w, b1.x, b1.y, b1.z, b1.w};
      #pragma unroll
      for (int i = 0; i < 8; ++i)
        #pragma unroll
        for (int j = 0; j < 8; ++j) v[i][j] += a[i] * b[j];
    }
  }

  #pragma unroll
  for (int i = 0; i < 8; ++i) {
    const int r = tp * 8 + i;
    const float4 m0 = *(const float4*)(mask + r * 128 + tq * 8);
    const float4 m1 = *(const float4*)(mask + r * 128 + tq * 8 + 4);
    const float mm[8] = {m0.x, m0.y, m0.z, m0.w, m1.x, m1.y, m1.z, m1.w};
    float s = 0.f;
    #pragma unroll
    for (int j = 0; j < 8; ++j) {
      const int c = tq * 8 + j;
      const float vv = (r == c) ? 0.0f : (v[i][j] + 1.0f) * 0.5f * mm[j];
      v[i][j] = vv;
      s += vv;
    }
    red[r][tq] = s;
  }
  __syncthreads();
  if (t < 128) {
    float sm = 0.f;
    #pragma unroll
    for (int u = 0; u < 16; ++u) sm += red[t][u];
    const float deg = 1.0f + sm;
    dinv_s[t] = (deg > 0.0f) ? rsqrtf(fmaxf(deg, 1e-12f)) : 0.0f;
  }
  __syncthreads();

  float dq[8];
  #pragma unroll
  for (int j = 0; j < 8; ++j) dq[j] = dinv_s[tq * 8 + j];
  float* Ab = An + (size_t)blk * 16384;
  #pragma unroll
  for (int i = 0; i < 8; ++i) {
    const int r = tp * 8 + i;
    const float dp = dinv_s[r];
    float o[8];
    #pragma unroll
    for (int j = 0; j < 8; ++j) {
      const int c = tq * 8 + j;
      o[j] = (r == c) ? dp * dq[j] : v[i][j] * dp * dq[j];
    }
    *(float4*)(Ab + (size_t)r * 128 + tq * 8)     = make_float4(o[0], o[1], o[2], o[3]);
    *(float4*)(Ab + (size_t)r * 128 + tq * 8 + 4) = make_float4(o[4], o[5], o[6], o[7]);
  }
}

// ---------------------------------------------------------------------------
// Tiled GEMM (layer 1): out[32768][256] = A @ W + bias. Grid (256,2).
// ---------------------------------------------------------------------------
__global__ __launch_bounds__(256) void k_gemm_t(
    const float* __restrict__ A, const float* __restrict__ W,
    const float* __restrict__ bias, float* __restrict__ out) {
  __shared__ float As[16][128];   // [k][row]
  __shared__ float Ws[16][128];   // [k][col]
  const int rb = blockIdx.x, cb = blockIdx.y;
  const int t = threadIdx.x, tp = t >> 4, tq = t & 15;
  const int m0 = rb * 128, c0 = cb * 128;

  float acc[8][8];
  #pragma unroll
  for (int j = 0; j < 8; ++j) {
    const float bj = bias[c0 + tq * 8 + j];
    #pragma unroll
    for (int i = 0; i < 8; ++i) acc[i][j] = bj;
  }

  for (int kc = 0; kc < 16; ++kc) {
    __syncthreads();
    #pragma unroll
    for (int l = 0; l < 2; ++l) {
      const int f = t + 256 * l;
      const int row = f >> 2, k4 = (f & 3) * 4;
      const float4 a4 = *(const float4*)(A + (size_t)(m0 + row) * 256 + kc * 16 + k4);
      As[k4 + 0][row] = a4.x;
      As[k4 + 1][row] = a4.y;
      As[k4 + 2][row] = a4.z;
      As[k4 + 3][row] = a4.w;
    }
    #pragma unroll
    for (int l = 0; l < 2; ++l) {
      const int f = t + 256 * l;
      const int k = f >> 5, c4 = (f & 31) * 4;
      const float4 w4 = *(const float4*)(W + (size_t)(kc * 16 + k) * 256 + c0 + c4);
      *(float4*)&Ws[k][c4] = w4;
    }
    __syncthreads();
    #pragma unroll
    for (int k = 0; k < 16; ++k) {
      const float4 a0 = *(const float4*)&As[k][tp * 8];
      const float4 a1 = *(const float4*)&As[k][tp * 8 + 4];
      const float4 w0 = *(const float4*)&Ws[k][tq * 8];
      const float4 w1 = *(const float4*)&Ws[k][tq * 8 + 4];
      const float a[8] = {a0.x, a0.y, a0.z, a0.w, a1.x, a1.y, a1.z, a1.w};
      const float w[8] = {w0.x, w0.y, w0.z, w0.w, w1.x, w1.y, w1.z, w1.w};
      #pragma unroll
      for (int i = 0; i < 8; ++i)
        #pragma unroll
        for (int j = 0; j < 8; ++j) acc[i][j] += a[i] * w[j];
    }
  }

  #pragma unroll
  for (int i = 0; i < 8; ++i) {
    float* orow = out + (size_t)(m0 + tp * 8 + i) * 256 + c0 + tq * 8;
    *(float4*)(orow)     = make_float4(acc[i][0], acc[i][1], acc[i][2], acc[i][3]);
    *(float4*)(orow + 4) = make_float4(acc[i][4], acc[i][5], acc[i][6], acc[i][7]);
  }
}

// ---------------------------------------------------------------------------
// Tiled GEMM (layer 2) with fused BN+ReLU on the A operand at staging time:
// a = fmax(pre*sc[col] + sh[col], 0). scsh: [0..255]=sc, [256..511]=sh.
// ---------------------------------------------------------------------------
__global__ __launch_bounds__(256) void k_gemmbn_t(
    const float* __restrict__ A, const float* __restrict__ scsh,
    const float* __restrict__ W, const float* __restrict__ bias,
    float* __restrict__ out) {
  __shared__ float As[16][128];
  __shared__ float Ws[16][128];
  const int rb = blockIdx.x, cb = blockIdx.y;
  const int t = threadIdx.x, tp = t >> 4, tq = t & 15;
  const int m0 = rb * 128, c0 = cb * 128;

  float acc[8][8];
  #pragma unroll
  for (int j = 0; j < 8; ++j) {
    const float bj = bias[c0 + tq * 8 + j];
    #pragma unroll
    for (int i = 0; i < 8; ++i) acc[i][j] = bj;
  }

  for (int kc = 0; kc < 16; ++kc) {
    __syncthreads();
    #pragma unroll
    for (int l = 0; l < 2; ++l) {
      const int f = t + 256 * l;
      const int row = f >> 2, k4 = (f & 3) * 4;
      const int col = kc * 16 + k4;                 // channel of h1
      const float4 a4 = *(const float4*)(A + (size_t)(m0 + row) * 256 + col);
      const float4 sc = *(const float4*)(scsh + col);
      const float4 sh = *(const float4*)(scsh + 256 + col);
      As[k4 + 0][row] = fmaxf(a4.x * sc.x + sh.x, 0.0f);
      As[k4 + 1][row] = fmaxf(a4.y * sc.y + sh.y, 0.0f);
      As[k4 + 2][row] = fmaxf(a4.z * sc.z + sh.z, 0.0f);
      As[k4 + 3][row] = fmaxf(a4.w * sc.w + sh.w, 0.0f);
    }
    #pragma unroll
    for (int l = 0; l < 2; ++l) {
      const int f = t + 256 * l;
      const int k = f >> 5, c4 = (f & 31) * 4;
      const float4 w4 = *(const float4*)(W + (size_t)(kc * 16 + k) * 256 + c0 + c4);
      *(float4*)&Ws[k][c4] = w4;
    }
    __syncthreads();
    #pragma unroll
    for (int k = 0; k < 16; ++k) {
      const float4 a0 = *(const float4*)&As[k][tp * 8];
      const float4 a1 = *(const float4*)&As[k][tp * 8 + 4];
      const float4 w0 = *(const float4*)&Ws[k][tq * 8];
      const float4 w1 = *(const float4*)&Ws[k][tq * 8 + 4];
      const float a[8] = {a0.x, a0.y, a0.z, a0.w, a1.x, a1.y, a1.z, a1.w};
      const float w[8] = {w0.x, w0.y, w0.z, w0.w, w1.x, w1.y, w1.z, w1.w};
      #pragma unroll
      for (int i = 0; i < 8; ++i)
        #pragma unroll
        for (int j = 0; j < 8; ++j) acc[i][j] += a[i] * w[j];
    }
  }

  #pragma unroll
  for (int i = 0; i < 8; ++i) {
    float* orow = out + (size_t)(m0 + tp * 8 + i) * 256 + c0 + tq * 8;
    *(float4*)(orow)     = make_float4(acc[i][0], acc[i][1], acc[i][2], acc[i][3]);
    *(float4*)(orow + 4) = make_float4(acc[i][4], acc[i][5], acc[i][6], acc[i][7]);
  }
}

// ---------------------------------------------------------------------------
// Tiled bmm + fused BN-stat partials. Grid (256 blks x 2 colblocks).
// ---------------------------------------------------------------------------
__global__ __launch_bounds__(256) void k_bmmst(
    const float* __restrict__ An, const float* __restrict__ XW,
    float* __restrict__ out, float* __restrict__ part) {
  __shared__ float As[16][128];   // [q][p]
  __shared__ float Ws[16][128];   // [q][c]
  __shared__ float rs[16][128];   // col-sum partial per tp group
  __shared__ float rq[16][128];   // col-sumsq partial
  const int blk = blockIdx.x, cb = blockIdx.y;
  const int t = threadIdx.x, tp = t >> 4, tq = t & 15;
  const float* Ab = An + (size_t)blk * 16384;
  const float* Xb = XW + (size_t)blk * (128 * 256);

  float acc[8][8];
  #pragma unroll
  for (int i = 0; i < 8; ++i)
    #pragma unroll
    for (int j = 0; j < 8; ++j) acc[i][j] = 0.f;

  for (int kc = 0; kc < 8; ++kc) {
    __syncthreads();
    #pragma unroll
    for (int l = 0; l < 2; ++l) {
      const int f = t + 256 * l;
      const int row = f >> 2, k4 = (f & 3) * 4;
      const float4 a4 = *(const float4*)(Ab + (size_t)row * 128 + kc * 16 + k4);
      As[k4 + 0][row] = a4.x;
      As[k4 + 1][row] = a4.y;
      As[k4 + 2][row] = a4.z;
      As[k4 + 3][row] = a4.w;
    }
    #pragma unroll
    for (int l = 0; l < 2; ++l) {
      const int f = t + 256 * l;
      const int k = f >> 5, c4 = (f & 31) * 4;
      const float4 w4 = *(const float4*)(Xb + (size_t)(kc * 16 + k) * 256 + cb * 128 + c4);
      *(float4*)&Ws[k][c4] = w4;
    }
    __syncthreads();
    #pragma unroll
    for (int k = 0; k < 16; ++k) {
      const float4 a0 = *(const float4*)&As[k][tp * 8];
      const float4 a1 = *(const float4*)&As[k][tp * 8 + 4];
      const float4 w0 = *(const float4*)&Ws[k][tq * 8];
      const float4 w1 = *(const float4*)&Ws[k][tq * 8 + 4];
      const float a[8] = {a0.x, a0.y, a0.z, a0.w, a1.x, a1.y, a1.z, a1.w};
      const float w[8] = {w0.x, w0.y, w0.z, w0.w, w1.x, w1.y, w1.z, w1.w};
      #pragma unroll
      for (int i = 0; i < 8; ++i)
        #pragma unroll
        for (int j = 0; j < 8; ++j) acc[i][j] += a[i] * w[j];
    }
  }

  // per-thread column partials (8 rows) -> LDS -> 128-thread final
  #pragma unroll
  for (int j = 0; j < 8; ++j) {
    float cs = 0.f, cq = 0.f;
    #pragma unroll
    for (int i = 0; i < 8; ++i) { cs += acc[i][j]; cq += acc[i][j] * acc[i][j]; }
    rs[tp][tq * 8 + j] = cs;
    rq[tp][tq * 8 + j] = cq;
  }
  __syncthreads();
  if (t < 128) {
    float s = 0.f, q = 0.f;
    #pragma unroll
    for (int u = 0; u < 16; ++u) { s += rs[u][t]; q += rq[u][t]; }
    const int base = (blk * 2 + cb) * 256;
    part[base + t]       = s;
    part[base + 128 + t] = q;
  }

  #pragma unroll
  for (int i = 0; i < 8; ++i) {
    float* orow = out + (size_t)(blk * 128 + tp * 8 + i) * 256 + cb * 128 + tq * 8;
    *(float4*)(orow)     = make_float4(acc[i][0], acc[i][1], acc[i][2], acc[i][3]);
    *(float4*)(orow + 4) = make_float4(acc[i][4], acc[i][5], acc[i][6], acc[i][7]);
  }
}

// ---------------------------------------------------------------------------
// bn final + scsh fused: per channel, sum 512 block-partials (same order as
// before: blk 0..255, cb = c>>7), then sc/sh. Deterministic.
// ---------------------------------------------------------------------------
__global__ __launch_bounds__(256) void k_bnscsh(
    const float* __restrict__ part, const float* __restrict__ g,
    const float* __restrict__ be, float* __restrict__ scsh) {
  const int c = threadIdx.x;
  const int cb = c >> 7, lc = c & 127;
  float s = 0.f, q = 0.f;
  for (int blk = 0; blk < 256; ++blk) {
    const float* pb = part + (size_t)(blk * 2 + cb) * 256;
    s += pb[lc];
    q += pb[128 + lc];
  }
  const float m = s * (1.0f / 32768.0f);
  const float var = q * (1.0f / 32768.0f) - m * m;
  const float sc = g[c] * rsqrtf(var + 1e-5f);
  scsh[c] = sc;
  scsh[256 + c] = be[c] - m * sc;
}

// ---------------------------------------------------------------------------
// head split-K GEMM v3: 1024 blocks (K-chunk 128) x 256 thr.
// Graph chunk (64 rows x 128 k) staged in LDS with BN+ReLU applied ONCE at
// staging (was recomputed 32x and re-read 32x from L1 per block). Inner loop
// streams Wm1 and reads graph via broadcast ds_read_b128. Partials to part
// (1024 x 8192), reduction tree identical to the verified Round-2 scheme.
// ---------------------------------------------------------------------------
__global__ __launch_bounds__(256) void k_headgemm_v3(
    const float* __restrict__ pre2, const float* __restrict__ scsh,
    const float* __restrict__ Wm1, float* __restrict__ part) {
  __shared__ float graphS[64][128];   // 32 KB
  const int t = threadIdx.x;
  const int bid = blockIdx.x;
  const int k0 = bid * 128;
  const int cbase = k0 & 255;         // channel base (0 or 128)

  // stage: 2048 float4s, BN+ReLU applied here, ascending k within each row
  #pragma unroll
  for (int l = 0; l < 8; ++l) {
    const int f = t + 256 * l;
    const int row = f >> 5, c4 = (f & 31) * 4;
    const float4 p = *(const float4*)(pre2 + (size_t)row * FEAT_ + k0 + c4);
    const float4 sc = *(const float4*)(scsh + cbase + c4);
    const float4 sh = *(const float4*)(scsh + 256 + cbase + c4);
    graphS[row][c4 + 0] = fmaxf(p.x * sc.x + sh.x, 0.0f);
    graphS[row][c4 + 1] = fmaxf(p.y * sc.y + sh.y, 0.0f);
    graphS[row][c4 + 2] = fmaxf(p.z * sc.z + sh.z, 0.0f);
    graphS[row][c4 + 3] = fmaxf(p.w * sc.w + sh.w, 0.0f);
  }
  __syncthreads();

  const int hg = t & 31;   // cols hg*4..+3
  const int bg = t >> 5;   // rows bg*8..+7
  float acc[8][4];
  #pragma unroll
  for (int i = 0; i < 8; ++i)
    #pragma unroll
    for (int j = 0; j < 4; ++j) acc[i][j] = 0.f;

  #pragma unroll 2
  for (int kk = 0; kk < 128; kk += 4) {
    const int k = k0 + kk;
    const float4 w0 = *(const float4*)(Wm1 + (size_t)(k + 0) * 128 + hg * 4);
    const float4 w1 = *(const float4*)(Wm1 + (size_t)(k + 1) * 128 + hg * 4);
    const float4 w2 = *(const float4*)(Wm1 + (size_t)(k + 2) * 128 + hg * 4);
    const float4 w3 = *(const float4*)(Wm1 + (size_t)(k + 3) * 128 + hg * 4);
    #pragma unroll
    for (int i = 0; i < 8; ++i) {
      const float4 a = *(const float4*)&graphS[bg * 8 + i][kk];
      acc[i][0] += a.x * w0.x; acc[i][1] += a.x * w0.y;
      acc[i][2] += a.x * w0.z; acc[i][3] += a.x * w0.w;
      acc[i][0] += a.y * w1.x; acc[i][1] += a.y * w1.y;
      acc[i][2] += a.y * w1.z; acc[i][3] += a.y * w1.w;
      acc[i][0] += a.z * w2.x; acc[i][1] += a.z * w2.y;
      acc[i][2] += a.z * w2.z; acc[i][3] += a.z * w2.w;
      acc[i][0] += a.w * w3.x; acc[i][1] += a.w * w3.y;
      acc[i][2] += a.w * w3.z; acc[i][3] += a.w * w3.w;
    }
  }

  float* pb = part + (size_t)bid * 8192;
  #pragma unroll
  for (int i = 0; i < 8; ++i)
    *(float4*)(pb + (bg * 8 + i) * 128 + hg * 4) =
        make_float4(acc[i][0], acc[i][1], acc[i][2], acc[i][3]);
}

// ---------------------------------------------------------------------------
// head reduce stage A: part2[jg][o] = sum_{j=jg*128..+127} part[j][o]
// grid (32, 8) x 256 thr; coalesced, deterministic (= verified R2 tree).
// ---------------------------------------------------------------------------
__global__ __launch_bounds__(256) void k_headredA(
    const float* __restrict__ part, float* __restrict__ part2) {
  const int o = blockIdx.x * 256 + threadIdx.x;
  const int jg = blockIdx.y;
  const float* base = part + (size_t)jg * 128 * 8192;
  float s = 0.f;
  for (int j = 0; j < 128; ++j) s += base[(size_t)j * 8192 + o];
  part2[(size_t)jg * 8192 + o] = s;
}

// head reduce stage B: z1[o] = sum_{jg<8} part2[jg][o]
__global__ __launch_bounds__(256) void k_headredB(
    const float* __restrict__ part2, float* __restrict__ z1) {
  const int o = blockIdx.x * 256 + threadIdx.x;
  float s = 0.f;
  #pragma unroll
  for (int jg = 0; jg < 8; ++jg) s += part2[(size_t)jg * 8192 + o];
  z1[o] = s;
}

// ---------------------------------------------------------------------------
// head BN over batch (J features) + ReLU
// ---------------------------------------------------------------------------
template <int J>
__global__ __launch_bounds__(64) void k_headbn(
    const float* __restrict__ z, const float* __restrict__ g,
    const float* __restrict__ be, float* __restrict__ zr) {
  __shared__ float rs[64], rs2[64];
  const int j = blockIdx.x, b = threadIdx.x;
  const float v = z[b * J + j];
  rs[b] = v; rs2[b] = v * v; __syncthreads();
  for (int s = 32; s; s >>= 1) {
    if (b < s) { rs[b] += rs[b + s]; rs2[b] += rs2[b + s]; }
    __syncthreads();
  }
  const float m = rs[0] * (1.0f / 64.0f);
  const float var = rs2[0] * (1.0f / 64.0f) - m * m;
  const float sc = g[j] * rsqrtf(var + 1e-5f);
  const float sh = be[j] - m * sc;
  zr[b * J + j] = fmaxf(v * sc + sh, 0.0f);
}

__global__ __launch_bounds__(64) void k_headmm2(
    const float* __restrict__ zr1, const float* __restrict__ Wm2,
    float* __restrict__ z2) {
  const int b = blockIdx.x, j = threadIdx.x;
  float acc = 0.f;
  for (int k = 0; k < 128; ++k) acc += zr1[b * 128 + k] * Wm2[k * 64 + j];
  z2[b * 64 + j] = acc;
}

__global__ __launch_bounds__(128) void k_headout(
    const float* __restrict__ zr2, const float* __restrict__ Wm3,
    const float* __restrict__ bm3, float* __restrict__ out) {
  const int t = threadIdx.x;
  const int b = t >> 1, c = t & 1;
  float s = bm3[c];
  for (int k = 0; k < 64; ++k) s += zr2[b * 64 + k] * Wm3[k * 2 + c];
  out[t] = s;
}

// ---------------------------------------------------------------------------
extern "C" void kernel_launch(void* const* d_in, const int* in_sizes, int n_in,
                              void* d_out, int out_size, void* d_ws, size_t ws_size,
                              hipStream_t stream) {
  (void)in_sizes; (void)n_in; (void)out_size; (void)ws_size;
  const float* x    = (const float*)d_in[0];
  const float* mask = (const float*)d_in[1];
  const float* W1   = (const float*)d_in[2];
  const float* b1   = (const float*)d_in[3];
  const float* g1   = (const float*)d_in[4];
  const float* be1  = (const float*)d_in[5];
  const float* W2   = (const float*)d_in[6];
  const float* b2   = (const float*)d_in[7];
  const float* g2   = (const float*)d_in[8];
  const float* be2  = (const float*)d_in[9];
  const float* Wm1  = (const float*)d_in[10];
  // d_in[11] = bm1 (zeros; cancels under BN)
  const float* gm1  = (const float*)d_in[12];
  const float* bem1 = (const float*)d_in[13];
  const float* Wm2  = (const float*)d_in[14];
  // d_in[15] = bm2 (zeros; cancels under BN)
  const float* gm2  = (const float*)d_in[16];
  const float* bem2 = (const float*)d_in[17];
  const float* Wm3  = (const float*)d_in[18];
  const float* bm3  = (const float*)d_in[19];

  // workspace (floats), same extent as verified previously (117.67 MB)
  float* ws   = (float*)d_ws;
  float* T1   = ws;                 // 8,388,608 : xn -> bn partials
  float* An   = T1 + 8388608;       // 4,194,304 : An -> head part2
  float* T2   = An + 4194304;       // 8,388,608 : XW1 -> XW2 -> head partials
  float* T3   = T2 + 8388608;       // 8,388,608 : pre1 -> pre2
  float* z1   = T3 + 8388608;       // 8,192
  float* dinv = z1 + 8192;          // 32,768 : scsh1 at +0, scsh2 at +512
  float* st1  = dinv + 32768;       // 512 (unused, kept for layout)
  float* st2  = st1 + 512;          // 512 (unused)
  float* zr1  = st2 + 512;          // 8,192
  float* z2   = zr1 + 8192;         // 4,096
  float* zr2  = z2 + 4096;          // 4,096

  float* scsh1 = dinv;
  float* scsh2 = dinv + 512;

  // edges / An (fused: sim + deg + normalize)
  k_xn<<<8192, 256, 0, stream>>>(x, T1);
  k_simfused<<<256, 256, 0, stream>>>(T1, mask, An);

  // layer 1: pre1 = An @ (x@W1+b1); stats fused into bmm
  k_gemm_t<<<dim3(256, 2), 256, 0, stream>>>(x, W1, b1, T2);
  k_bmmst<<<dim3(256, 2), 256, 0, stream>>>(An, T2, T3, T1);   // T1: xn dead
  k_bnscsh<<<1, 256, 0, stream>>>(T1, g1, be1, scsh1);

  // layer 2: pre2 = An @ (relu(bn(pre1))@W2+b2); bn fused into A-staging
  k_gemmbn_t<<<dim3(256, 2), 256, 0, stream>>>(T3, scsh1, W2, b2, T2);
  k_bmmst<<<dim3(256, 2), 256, 0, stream>>>(An, T2, T3, T1);
  k_bnscsh<<<1, 256, 0, stream>>>(T1, g2, be2, scsh2);

  // head: z1 = relu(bn(pre2)) @ Wm1, LDS-staged split-K + 2-stage reduce
  k_headgemm_v3<<<1024, 256, 0, stream>>>(T3, scsh2, Wm1, T2);
  k_headredA<<<dim3(32, 8), 256, 0, stream>>>(T2, An);
  k_headredB<<<32, 256, 0, stream>>>(An, z1);
  k_headbn<128><<<128, 64, 0, stream>>>(z1, gm1, bem1, zr1);
  k_headmm2<<<64, 64, 0, stream>>>(zr1, Wm2, z2);
  k_headbn<64><<<64, 64, 0, stream>>>(z2, gm2, bem2, zr2);
  k_headout<<<1, 128, 0, stream>>>(zr2, Wm3, bm3, (float*)d_out);
}

// Round 7
// 439.234 us; speedup vs baseline: 5.9166x; 1.0430x over previous
//
#include <hip/hip_runtime.h>
#include <cstdint>
#include <cstddef>

// Shapes (fixed): B=64, N=4, P=128, d=h=256, totP=512, feat=131072
#define P_    128
#define H_    256
#define FEAT_ 131072

// ---------------------------------------------------------------------------
// xn: row-normalize x. 8192 blocks x 256 thr; one wave per row, float4 loads,
// wave-shuffle reduce.
// ---------------------------------------------------------------------------
__global__ __launch_bounds__(256) void k_xn(
    const float* __restrict__ x, float* __restrict__ xn) {
  const int t = threadIdx.x;
  const int lane = t & 63;
  const int row = blockIdx.x * 4 + (t >> 6);
  const float* xr = x + (size_t)row * 256;
  const float4 v = *(const float4*)(xr + lane * 4);
  float ss = v.x * v.x + v.y * v.y + v.z * v.z + v.w * v.w;
  #pragma unroll
  for (int s = 32; s; s >>= 1) ss += __shfl_xor(ss, s, 64);
  const float inv = 1.0f / fmaxf(sqrtf(ss), 1e-12f);
  *(float4*)(xn + (size_t)row * 256 + lane * 4) =
      make_float4(v.x * inv, v.y * inv, v.z * inv, v.w * inv);
}

// ---------------------------------------------------------------------------
// Fused sim + deg + sym-normalize. One block per blk (256 blocks, 256 thr).
// ---------------------------------------------------------------------------
__global__ __launch_bounds__(256) void k_simfused(
    const float* __restrict__ xn, const float* __restrict__ mask,
    float* __restrict__ An) {
  __shared__ float Xs[16][128];      // [k][row], chunk of K
  __shared__ float red[128][17];     // row partial sums
  __shared__ float dinv_s[128];
  const int blk = blockIdx.x;
  const int t = threadIdx.x;
  const int tp = t >> 4, tq = t & 15;   // rows tp*8..+7, cols tq*8..+7
  const float* Xb = xn + (size_t)blk * (128 * 256);

  float v[8][8];
  #pragma unroll
  for (int i = 0; i < 8; ++i)
    #pragma unroll
    for (int j = 0; j < 8; ++j) v[i][j] = 0.f;

  for (int kc = 0; kc < 16; ++kc) {
    __syncthreads();
    #pragma unroll
    for (int l = 0; l < 2; ++l) {
      const int f = t + 256 * l;
      const int row = f >> 2, k4 = (f & 3) * 4;
      const float4 x4 = *(const float4*)(Xb + (size_t)row * 256 + kc * 16 + k4);
      Xs[k4 + 0][row] = x4.x;
      Xs[k4 + 1][row] = x4.y;
      Xs[k4 + 2][row] = x4.z;
      Xs[k4 + 3][row] = x4.w;
    }
    __syncthreads();
    #pragma unroll
    for (int k = 0; k < 16; ++k) {
      const float4 a0 = *(const float4*)&Xs[k][tp * 8];
      const float4 a1 = *(const float4*)&Xs[k][tp * 8 + 4];
      const float4 b0 = *(const float4*)&Xs[k][tq * 8];
      const float4 b1 = *(const float4*)&Xs[k][tq * 8 + 4];
      const float a[8] = {a0.x, a0.y, a0.z, a0.w, a1.x, a1.y, a1.z, a1.w};
      const float b[8] = {b0.x, b0.y, b0.z, b0.w, b1.x, b1.y, b1.z, b1.w};
      #pragma unroll
      for (int i = 0; i < 8; ++i)
        #pragma unroll
        for (int j = 0; j < 8; ++j) v[i][j] += a[i] * b[j];
    }
  }

  #pragma unroll
  for (int i = 0; i < 8; ++i) {
    const int r = tp * 8 + i;
    const float4 m0 = *(const float4*)(mask + r * 128 + tq * 8);
    const float4 m1 = *(const float4*)(mask + r * 128 + tq * 8 + 4);
    const float mm[8] = {m0.x, m0.y, m0.z, m0.w, m1.x, m1.y, m1.z, m1.w};
    float s = 0.f;
    #pragma unroll
    for (int j = 0; j < 8; ++j) {
      const int c = tq * 8 + j;
      const float vv = (r == c) ? 0.0f : (v[i][j] + 1.0f) * 0.5f * mm[j];
      v[i][j] = vv;
      s += vv;
    }
    red[r][tq] = s;
  }
  __syncthreads();
  if (t < 128) {
    float sm = 0.f;
    #pragma unroll
    for (int u = 0; u < 16; ++u) sm += red[t][u];
    const float deg = 1.0f + sm;
    dinv_s[t] = (deg > 0.0f) ? rsqrtf(fmaxf(deg, 1e-12f)) : 0.0f;
  }
  __syncthreads();

  float dq[8];
  #pragma unroll
  for (int j = 0; j < 8; ++j) dq[j] = dinv_s[tq * 8 + j];
  float* Ab = An + (size_t)blk * 16384;
  #pragma unroll
  for (int i = 0; i < 8; ++i) {
    const int r = tp * 8 + i;
    const float dp = dinv_s[r];
    float o[8];
    #pragma unroll
    for (int j = 0; j < 8; ++j) {
      const int c = tq * 8 + j;
      o[j] = (r == c) ? dp * dq[j] : v[i][j] * dp * dq[j];
    }
    *(float4*)(Ab + (size_t)r * 128 + tq * 8)     = make_float4(o[0], o[1], o[2], o[3]);
    *(float4*)(Ab + (size_t)r * 128 + tq * 8 + 4) = make_float4(o[4], o[5], o[6], o[7]);
  }
}

// ---------------------------------------------------------------------------
// Tiled GEMM (layer 1): out[32768][256] = A @ W + bias.
// 64x128 tile, grid (512,2) = 1024 blocks (4/CU, 16 waves/CU). Per-thread
// 4x8. Column fragments split tq*4 / 64+tq*4 (2-way bank alias = free).
// Per-element math bitwise identical to 128-tile version (bias-first,
// ascending-k FMA).
// ---------------------------------------------------------------------------
__global__ __launch_bounds__(256) void k_gemm_t(
    const float* __restrict__ A, const float* __restrict__ W,
    const float* __restrict__ bias, float* __restrict__ out) {
  __shared__ float As[16][64];    // [k][row]
  __shared__ float Ws[16][128];   // [k][col]
  const int rb = blockIdx.x, cb = blockIdx.y;
  const int t = threadIdx.x, tp = t >> 4, tq = t & 15;
  const int m0 = rb * 64, c0 = cb * 128;

  float acc[4][8];
  #pragma unroll
  for (int j = 0; j < 8; ++j) {
    const int col = c0 + ((j < 4) ? (tq * 4 + j) : (64 + tq * 4 + j - 4));
    const float bj = bias[col];
    #pragma unroll
    for (int i = 0; i < 4; ++i) acc[i][j] = bj;
  }

  for (int kc = 0; kc < 16; ++kc) {
    __syncthreads();
    {   // stage A tile: 64 rows x 16 k (256 float4)
      const int row = t >> 2, k4 = (t & 3) * 4;
      const float4 a4 = *(const float4*)(A + (size_t)(m0 + row) * 256 + kc * 16 + k4);
      As[k4 + 0][row] = a4.x;
      As[k4 + 1][row] = a4.y;
      As[k4 + 2][row] = a4.z;
      As[k4 + 3][row] = a4.w;
    }
    #pragma unroll
    for (int l = 0; l < 2; ++l) {   // stage W tile: 16 k x 128 cols
      const int f = t + 256 * l;
      const int k = f >> 5, c4 = (f & 31) * 4;
      *(float4*)&Ws[k][c4] =
          *(const float4*)(W + (size_t)(kc * 16 + k) * 256 + c0 + c4);
    }
    __syncthreads();
    #pragma unroll
    for (int k = 0; k < 16; ++k) {
      const float4 av = *(const float4*)&As[k][tp * 4];
      const float4 w0 = *(const float4*)&Ws[k][tq * 4];
      const float4 w1 = *(const float4*)&Ws[k][64 + tq * 4];
      const float a[4] = {av.x, av.y, av.z, av.w};
      const float w[8] = {w0.x, w0.y, w0.z, w0.w, w1.x, w1.y, w1.z, w1.w};
      #pragma unroll
      for (int i = 0; i < 4; ++i)
        #pragma unroll
        for (int j = 0; j < 8; ++j) acc[i][j] += a[i] * w[j];
    }
  }

  #pragma unroll
  for (int i = 0; i < 4; ++i) {
    float* orow = out + (size_t)(m0 + tp * 4 + i) * 256 + c0;
    *(float4*)(orow + tq * 4)      = make_float4(acc[i][0], acc[i][1], acc[i][2], acc[i][3]);
    *(float4*)(orow + 64 + tq * 4) = make_float4(acc[i][4], acc[i][5], acc[i][6], acc[i][7]);
  }
}

// ---------------------------------------------------------------------------
// Tiled GEMM (layer 2), same 64x128 structure, with fused BN+ReLU on the A
// operand at staging time. scsh: [0..255]=sc, [256..511]=sh.
// ---------------------------------------------------------------------------
__global__ __launch_bounds__(256) void k_gemmbn_t(
    const float* __restrict__ A, const float* __restrict__ scsh,
    const float* __restrict__ W, const float* __restrict__ bias,
    float* __restrict__ out) {
  __shared__ float As[16][64];
  __shared__ float Ws[16][128];
  const int rb = blockIdx.x, cb = blockIdx.y;
  const int t = threadIdx.x, tp = t >> 4, tq = t & 15;
  const int m0 = rb * 64, c0 = cb * 128;

  float acc[4][8];
  #pragma unroll
  for (int j = 0; j < 8; ++j) {
    const int col = c0 + ((j < 4) ? (tq * 4 + j) : (64 + tq * 4 + j - 4));
    const float bj = bias[col];
    #pragma unroll
    for (int i = 0; i < 4; ++i) acc[i][j] = bj;
  }

  for (int kc = 0; kc < 16; ++kc) {
    __syncthreads();
    {   // stage A tile with BN+ReLU (channel = k index)
      const int row = t >> 2, k4 = (t & 3) * 4;
      const int col = kc * 16 + k4;
      const float4 a4 = *(const float4*)(A + (size_t)(m0 + row) * 256 + col);
      const float4 sc = *(const float4*)(scsh + col);
      const float4 sh = *(const float4*)(scsh + 256 + col);
      As[k4 + 0][row] = fmaxf(a4.x * sc.x + sh.x, 0.0f);
      As[k4 + 1][row] = fmaxf(a4.y * sc.y + sh.y, 0.0f);
      As[k4 + 2][row] = fmaxf(a4.z * sc.z + sh.z, 0.0f);
      As[k4 + 3][row] = fmaxf(a4.w * sc.w + sh.w, 0.0f);
    }
    #pragma unroll
    for (int l = 0; l < 2; ++l) {
      const int f = t + 256 * l;
      const int k = f >> 5, c4 = (f & 31) * 4;
      *(float4*)&Ws[k][c4] =
          *(const float4*)(W + (size_t)(kc * 16 + k) * 256 + c0 + c4);
    }
    __syncthreads();
    #pragma unroll
    for (int k = 0; k < 16; ++k) {
      const float4 av = *(const float4*)&As[k][tp * 4];
      const float4 w0 = *(const float4*)&Ws[k][tq * 4];
      const float4 w1 = *(const float4*)&Ws[k][64 + tq * 4];
      const float a[4] = {av.x, av.y, av.z, av.w};
      const float w[8] = {w0.x, w0.y, w0.z, w0.w, w1.x, w1.y, w1.z, w1.w};
      #pragma unroll
      for (int i = 0; i < 4; ++i)
        #pragma unroll
        for (int j = 0; j < 8; ++j) acc[i][j] += a[i] * w[j];
    }
  }

  #pragma unroll
  for (int i = 0; i < 4; ++i) {
    float* orow = out + (size_t)(m0 + tp * 4 + i) * 256 + c0;
    *(float4*)(orow + tq * 4)      = make_float4(acc[i][0], acc[i][1], acc[i][2], acc[i][3]);
    *(float4*)(orow + 64 + tq * 4) = make_float4(acc[i][4], acc[i][5], acc[i][6], acc[i][7]);
  }
}

// ---------------------------------------------------------------------------
// Tiled bmm + fused BN-stat partials. 64x128 tile: grid (256 blks, 4):
// y = rh*2+cb (row-half, col-half). Stats: per-block per-col sum/sumsq over
// its 64 rows -> part[(blk*4+y)*256 + {c | 128+c}]. Deterministic.
// ---------------------------------------------------------------------------
__global__ __launch_bounds__(256) void k_bmmst(
    const float* __restrict__ An, const float* __restrict__ XW,
    float* __restrict__ out, float* __restrict__ part) {
  __shared__ float As[16][64];    // [q][p]
  __shared__ float Ws[16][128];   // [q][c]
  __shared__ float rs[16][128];
  __shared__ float rq[16][128];
  const int blk = blockIdx.x;
  const int y = blockIdx.y;            // 0..3
  const int rh = y >> 1, cb = y & 1;
  const int t = threadIdx.x, tp = t >> 4, tq = t & 15;
  const float* Ab = An + (size_t)blk * 16384 + (size_t)rh * 64 * 128;
  const float* Xb = XW + (size_t)blk * (128 * 256);

  float acc[4][8];
  #pragma unroll
  for (int i = 0; i < 4; ++i)
    #pragma unroll
    for (int j = 0; j < 8; ++j) acc[i][j] = 0.f;

  for (int kc = 0; kc < 8; ++kc) {     // K=128
    __syncthreads();
    {   // stage An tile: 64 p x 16 q
      const int row = t >> 2, k4 = (t & 3) * 4;
      const float4 a4 = *(const float4*)(Ab + (size_t)row * 128 + kc * 16 + k4);
      As[k4 + 0][row] = a4.x;
      As[k4 + 1][row] = a4.y;
      As[k4 + 2][row] = a4.z;
      As[k4 + 3][row] = a4.w;
    }
    #pragma unroll
    for (int l = 0; l < 2; ++l) {      // stage XW tile: 16 q x 128 c
      const int f = t + 256 * l;
      const int k = f >> 5, c4 = (f & 31) * 4;
      *(float4*)&Ws[k][c4] =
          *(const float4*)(Xb + (size_t)(kc * 16 + k) * 256 + cb * 128 + c4);
    }
    __syncthreads();
    #pragma unroll
    for (int k = 0; k < 16; ++k) {
      const float4 av = *(const float4*)&As[k][tp * 4];
      const float4 w0 = *(const float4*)&Ws[k][tq * 4];
      const float4 w1 = *(const float4*)&Ws[k][64 + tq * 4];
      const float a[4] = {av.x, av.y, av.z, av.w};
      const float w[8] = {w0.x, w0.y, w0.z, w0.w, w1.x, w1.y, w1.z, w1.w};
      #pragma unroll
      for (int i = 0; i < 4; ++i)
        #pragma unroll
        for (int j = 0; j < 8; ++j) acc[i][j] += a[i] * w[j];
    }
  }

  // stats: per-thread col partial over 4 rows -> LDS -> 128-thread final
  #pragma unroll
  for (int j = 0; j < 8; ++j) {
    float cs = 0.f, cq = 0.f;
    #pragma unroll
    for (int i = 0; i < 4; ++i) { cs += acc[i][j]; cq += acc[i][j] * acc[i][j]; }
    const int col = (j < 4) ? (tq * 4 + j) : (64 + tq * 4 + j - 4);
    rs[tp][col] = cs;
    rq[tp][col] = cq;
  }
  __syncthreads();
  if (t < 128) {
    float s = 0.f, q = 0.f;
    #pragma unroll
    for (int u = 0; u < 16; ++u) { s += rs[u][t]; q += rq[u][t]; }
    const int base = (blk * 4 + y) * 256;
    part[base + t]       = s;
    part[base + 128 + t] = q;
  }

  #pragma unroll
  for (int i = 0; i < 4; ++i) {
    float* orow = out + (size_t)(blk * 128 + rh * 64 + tp * 4 + i) * 256 + cb * 128;
    *(float4*)(orow + tq * 4)      = make_float4(acc[i][0], acc[i][1], acc[i][2], acc[i][3]);
    *(float4*)(orow + 64 + tq * 4) = make_float4(acc[i][4], acc[i][5], acc[i][6], acc[i][7]);
  }
}

// ---------------------------------------------------------------------------
// bn final + scsh: block per channel (256 blocks x 256 thr). Thread u sums
// its blk's two row-halves (fixed order), then LDS tree. Deterministic.
// ---------------------------------------------------------------------------
__global__ __launch_bounds__(256) void k_bnscsh(
    const float* __restrict__ part, const float* __restrict__ g,
    const float* __restrict__ be, float* __restrict__ scsh) {
  __shared__ float ss[256], qq[256];
  const int c = blockIdx.x;
  const int cb = c >> 7, lc = c & 127;
  const int u = threadIdx.x;           // = blk
  const float* p0 = part + (size_t)(u * 4 + cb) * 256;        // rh=0
  const float* p1 = part + (size_t)(u * 4 + 2 + cb) * 256;    // rh=1
  ss[u] = p0[lc] + p1[lc];
  qq[u] = p0[128 + lc] + p1[128 + lc];
  __syncthreads();
  for (int st = 128; st; st >>= 1) {
    if (u < st) { ss[u] += ss[u + st]; qq[u] += qq[u + st]; }
    __syncthreads();
  }
  if (u == 0) {
    const float m = ss[0] * (1.0f / 32768.0f);
    const float var = qq[0] * (1.0f / 32768.0f) - m * m;
    const float sc = g[c] * rsqrtf(var + 1e-5f);
    scsh[c] = sc;
    scsh[256 + c] = be[c] - m * sc;
  }
}

// ---------------------------------------------------------------------------
// head split-K GEMM v3: 1024 blocks (K-chunk 128) x 256 thr. Graph chunk
// staged in LDS with BN+ReLU applied once. Partials -> part (1024 x 8192).
// ---------------------------------------------------------------------------
__global__ __launch_bounds__(256) void k_headgemm_v3(
    const float* __restrict__ pre2, const float* __restrict__ scsh,
    const float* __restrict__ Wm1, float* __restrict__ part) {
  __shared__ float graphS[64][128];   // 32 KB
  const int t = threadIdx.x;
  const int bid = blockIdx.x;
  const int k0 = bid * 128;
  const int cbase = k0 & 255;

  #pragma unroll
  for (int l = 0; l < 8; ++l) {
    const int f = t + 256 * l;
    const int row = f >> 5, c4 = (f & 31) * 4;
    const float4 p = *(const float4*)(pre2 + (size_t)row * FEAT_ + k0 + c4);
    const float4 sc = *(const float4*)(scsh + cbase + c4);
    const float4 sh = *(const float4*)(scsh + 256 + cbase + c4);
    graphS[row][c4 + 0] = fmaxf(p.x * sc.x + sh.x, 0.0f);
    graphS[row][c4 + 1] = fmaxf(p.y * sc.y + sh.y, 0.0f);
    graphS[row][c4 + 2] = fmaxf(p.z * sc.z + sh.z, 0.0f);
    graphS[row][c4 + 3] = fmaxf(p.w * sc.w + sh.w, 0.0f);
  }
  __syncthreads();

  const int hg = t & 31;
  const int bg = t >> 5;
  float acc[8][4];
  #pragma unroll
  for (int i = 0; i < 8; ++i)
    #pragma unroll
    for (int j = 0; j < 4; ++j) acc[i][j] = 0.f;

  #pragma unroll 2
  for (int kk = 0; kk < 128; kk += 4) {
    const int k = k0 + kk;
    const float4 w0 = *(const float4*)(Wm1 + (size_t)(k + 0) * 128 + hg * 4);
    const float4 w1 = *(const float4*)(Wm1 + (size_t)(k + 1) * 128 + hg * 4);
    const float4 w2 = *(const float4*)(Wm1 + (size_t)(k + 2) * 128 + hg * 4);
    const float4 w3 = *(const float4*)(Wm1 + (size_t)(k + 3) * 128 + hg * 4);
    #pragma unroll
    for (int i = 0; i < 8; ++i) {
      const float4 a = *(const float4*)&graphS[bg * 8 + i][kk];
      acc[i][0] += a.x * w0.x; acc[i][1] += a.x * w0.y;
      acc[i][2] += a.x * w0.z; acc[i][3] += a.x * w0.w;
      acc[i][0] += a.y * w1.x; acc[i][1] += a.y * w1.y;
      acc[i][2] += a.y * w1.z; acc[i][3] += a.y * w1.w;
      acc[i][0] += a.z * w2.x; acc[i][1] += a.z * w2.y;
      acc[i][2] += a.z * w2.z; acc[i][3] += a.z * w2.w;
      acc[i][0] += a.w * w3.x; acc[i][1] += a.w * w3.y;
      acc[i][2] += a.w * w3.z; acc[i][3] += a.w * w3.w;
    }
  }

  float* pb = part + (size_t)bid * 8192;
  #pragma unroll
  for (int i = 0; i < 8; ++i)
    *(float4*)(pb + (bg * 8 + i) * 128 + hg * 4) =
        make_float4(acc[i][0], acc[i][1], acc[i][2], acc[i][3]);
}

// ---------------------------------------------------------------------------
// head reduce stage A: part2[jg][o] = sum of 128 consecutive partials.
// ---------------------------------------------------------------------------
__global__ __launch_bounds__(256) void k_headredA(
    const float* __restrict__ part, float* __restrict__ part2) {
  const int o = blockIdx.x * 256 + threadIdx.x;
  const int jg = blockIdx.y;
  const float* base = part + (size_t)jg * 128 * 8192;
  float s = 0.f;
  for (int j = 0; j < 128; ++j) s += base[(size_t)j * 8192 + o];
  part2[(size_t)jg * 8192 + o] = s;
}

// head reduce stage B: z1[o] = sum_{jg<8} part2[jg][o]
__global__ __launch_bounds__(256) void k_headredB(
    const float* __restrict__ part2, float* __restrict__ z1) {
  const int o = blockIdx.x * 256 + threadIdx.x;
  float s = 0.f;
  #pragma unroll
  for (int jg = 0; jg < 8; ++jg) s += part2[(size_t)jg * 8192 + o];
  z1[o] = s;
}

// ---------------------------------------------------------------------------
// head BN over batch (J features) + ReLU
// ---------------------------------------------------------------------------
template <int J>
__global__ __launch_bounds__(64) void k_headbn(
    const float* __restrict__ z, const float* __restrict__ g,
    const float* __restrict__ be, float* __restrict__ zr) {
  __shared__ float rs[64], rs2[64];
  const int j = blockIdx.x, b = threadIdx.x;
  const float v = z[b * J + j];
  rs[b] = v; rs2[b] = v * v; __syncthreads();
  for (int s = 32; s; s >>= 1) {
    if (b < s) { rs[b] += rs[b + s]; rs2[b] += rs2[b + s]; }
    __syncthreads();
  }
  const float m = rs[0] * (1.0f / 64.0f);
  const float var = rs2[0] * (1.0f / 64.0f) - m * m;
  const float sc = g[j] * rsqrtf(var + 1e-5f);
  const float sh = be[j] - m * sc;
  zr[b * J + j] = fmaxf(v * sc + sh, 0.0f);
}

__global__ __launch_bounds__(64) void k_headmm2(
    const float* __restrict__ zr1, const float* __restrict__ Wm2,
    float* __restrict__ z2) {
  const int b = blockIdx.x, j = threadIdx.x;
  float acc = 0.f;
  for (int k = 0; k < 128; ++k) acc += zr1[b * 128 + k] * Wm2[k * 64 + j];
  z2[b * 64 + j] = acc;
}

__global__ __launch_bounds__(128) void k_headout(
    const float* __restrict__ zr2, const float* __restrict__ Wm3,
    const float* __restrict__ bm3, float* __restrict__ out) {
  const int t = threadIdx.x;
  const int b = t >> 1, c = t & 1;
  float s = bm3[c];
  for (int k = 0; k < 64; ++k) s += zr2[b * 64 + k] * Wm3[k * 2 + c];
  out[t] = s;
}

// ---------------------------------------------------------------------------
extern "C" void kernel_launch(void* const* d_in, const int* in_sizes, int n_in,
                              void* d_out, int out_size, void* d_ws, size_t ws_size,
                              hipStream_t stream) {
  (void)in_sizes; (void)n_in; (void)out_size; (void)ws_size;
  const float* x    = (const float*)d_in[0];
  const float* mask = (const float*)d_in[1];
  const float* W1   = (const float*)d_in[2];
  const float* b1   = (const float*)d_in[3];
  const float* g1   = (const float*)d_in[4];
  const float* be1  = (const float*)d_in[5];
  const float* W2   = (const float*)d_in[6];
  const float* b2   = (const float*)d_in[7];
  const float* g2   = (const float*)d_in[8];
  const float* be2  = (const float*)d_in[9];
  const float* Wm1  = (const float*)d_in[10];
  // d_in[11] = bm1 (zeros; cancels under BN)
  const float* gm1  = (const float*)d_in[12];
  const float* bem1 = (const float*)d_in[13];
  const float* Wm2  = (const float*)d_in[14];
  // d_in[15] = bm2 (zeros; cancels under BN)
  const float* gm2  = (const float*)d_in[16];
  const float* bem2 = (const float*)d_in[17];
  const float* Wm3  = (const float*)d_in[18];
  const float* bm3  = (const float*)d_in[19];

  // workspace (floats), same extent as verified previously (117.67 MB)
  float* ws   = (float*)d_ws;
  float* T1   = ws;                 // 8,388,608 : xn -> bn partials
  float* An   = T1 + 8388608;       // 4,194,304 : An -> head part2
  float* T2   = An + 4194304;       // 8,388,608 : XW1 -> XW2 -> head partials
  float* T3   = T2 + 8388608;       // 8,388,608 : pre1 -> pre2
  float* z1   = T3 + 8388608;       // 8,192
  float* dinv = z1 + 8192;          // 32,768 : scsh1 at +0, scsh2 at +512
  float* st1  = dinv + 32768;       // 512 (unused, kept for layout)
  float* st2  = st1 + 512;          // 512 (unused)
  float* zr1  = st2 + 512;          // 8,192
  float* z2   = zr1 + 8192;         // 4,096
  float* zr2  = z2 + 4096;          // 4,096

  float* scsh1 = dinv;
  float* scsh2 = dinv + 512;

  // edges / An (fused: sim + deg + normalize)
  k_xn<<<8192, 256, 0, stream>>>(x, T1);
  k_simfused<<<256, 256, 0, stream>>>(T1, mask, An);

  // layer 1: pre1 = An @ (x@W1+b1); stats fused into bmm
  k_gemm_t<<<dim3(512, 2), 256, 0, stream>>>(x, W1, b1, T2);
  k_bmmst<<<dim3(256, 4), 256, 0, stream>>>(An, T2, T3, T1);   // T1: xn dead
  k_bnscsh<<<256, 256, 0, stream>>>(T1, g1, be1, scsh1);

  // layer 2: pre2 = An @ (relu(bn(pre1))@W2+b2); bn fused into A-staging
  k_gemmbn_t<<<dim3(512, 2), 256, 0, stream>>>(T3, scsh1, W2, b2, T2);
  k_bmmst<<<dim3(256, 4), 256, 0, stream>>>(An, T2, T3, T1);
  k_bnscsh<<<256, 256, 0, stream>>>(T1, g2, be2, scsh2);

  // head: z1 = relu(bn(pre2)) @ Wm1, LDS-staged split-K + 2-stage reduce
  k_headgemm_v3<<<1024, 256, 0, stream>>>(T3, scsh2, Wm1, T2);
  k_headredA<<<dim3(32, 8), 256, 0, stream>>>(T2, An);
  k_headredB<<<32, 256, 0, stream>>>(An, z1);
  k_headbn<128><<<128, 64, 0, stream>>>(z1, gm1, bem1, zr1);
  k_headmm2<<<64, 64, 0, stream>>>(zr1, Wm2, z2);
  k_headbn<64><<<64, 64, 0, stream>>>(z2, gm2, bem2, zr2);
  k_headout<<<1, 128, 0, stream>>>(zr2, Wm3, bm3, (float*)d_out);
}